// Round 2
// 255.100 us; speedup vs baseline: 1.0250x; 1.0250x over previous
//
#include <hip/hip_runtime.h>
#include <stdint.h>

// MultiHeadAttention: B=2, S=2048, D=1024, H=16, Dh=64. fp32 in/out, bf16 MFMA inside.
// R10: isolation round. Keeps R9's 8-wave/512-thread attn restructure (occupancy
// 8 -> ~16 waves/CU) but reverts R9's two numerics changes to R8's proven forms:
// in-attn score scale (exp2f(sA*c)) and scalar f2bf P-packing. GEMM epilogue back
// to R8 (no scale). If this passes, R9's NaN was a numerics change; if it fails,
// the restructure itself is unsound and gets reverted.

typedef unsigned short u16;
typedef short s16x8 __attribute__((ext_vector_type(8)));   // 8 bf16 (4 VGPR)
typedef short s16x4 __attribute__((ext_vector_type(4)));   // 4 bf16 (2 VGPR)
typedef float f32x4 __attribute__((ext_vector_type(4)));
typedef u16 u16x4 __attribute__((ext_vector_type(4)));

#define S_LEN 2048
#define DMODEL 1024
#define LOG2E 1.44269504088896340736f

__device__ __forceinline__ u16 f2bf(float f) {
  union { float f; uint32_t u; } v; v.f = f;
  return (u16)((v.u + 0x8000u) >> 16);
}

__device__ __forceinline__ s16x8 ld8f(const float* s) {  // 8 fp32 -> 8 bf16
  f32x4 a = *(const f32x4*)s;
  f32x4 b = *(const f32x4*)(s + 4);
  s16x8 r;
  r[0] = (short)f2bf(a[0]); r[1] = (short)f2bf(a[1]);
  r[2] = (short)f2bf(a[2]); r[3] = (short)f2bf(a[3]);
  r[4] = (short)f2bf(b[0]); r[5] = (short)f2bf(b[1]);
  r[6] = (short)f2bf(b[2]); r[7] = (short)f2bf(b[3]);
  return r;
}

// async global->LDS, 16B/lane; HW scatters lane i to ldsbase + i*16
__device__ __forceinline__ void gl2lds16(const u16* g, u16* l) {
  __builtin_amdgcn_global_load_lds(
      (const __attribute__((address_space(1))) uint32_t*)g,
      (__attribute__((address_space(3))) uint32_t*)l, 16, 0, 0);
}

// ---------------------------------------------------------------------------
// fp32 -> bf16 conversion: 4 weights (1M elem) + 3 activations (4.19M elem).
// ---------------------------------------------------------------------------
struct Cvt7 { const float* s[7]; u16* d[7]; int n[7]; };

__global__ __launch_bounds__(256) void cvt7(Cvt7 p) {
  const int z = blockIdx.y;
  const int idx = blockIdx.x * 256 + threadIdx.x;
  if (idx * 8 < p.n[z])
    *(s16x8*)(p.d[z] + (size_t)idx * 8) = ld8f(p.s[z] + (size_t)idx * 8);
}

// ---------------------------------------------------------------------------
// GEMM: C[M,N] = A[M,K] @ W[N,K]^T + bias[N]; A,W bf16, bias fp32.  (R8 form)
// OUT_F32=false -> C bf16 (QKV), OUT_F32=true -> C fp32 (O projection).
// 128x128 tile, BK=64, 4 waves (2x2 of 64x64), m97-style global_load_lds.
// ---------------------------------------------------------------------------
struct GemmBatch {
  const u16* A[3]; const u16* W[3]; const float* Bv[3]; void* C[3];
};

template <bool OUT_F32>
__global__ __launch_bounds__(256) void gemm_bt(GemmBatch p, int M, int N, int K) {
  __shared__ u16 As[128 * 64];
  __shared__ u16 Ws[128 * 64];
  const int z = blockIdx.z;
  const u16* __restrict__ A      = p.A[z];
  const u16* __restrict__ W      = p.W[z];
  const float* __restrict__ bias = p.Bv[z];

  const int tid = threadIdx.x;
  const int wave = tid >> 6, lane = tid & 63;
  const int quad = lane >> 4, l16 = lane & 15;
  const int bm = blockIdx.y * 128, bn = blockIdx.x * 128;
  const int wr = (wave >> 1) * 64, wc = (wave & 1) * 64;
  const int sr8 = lane >> 3;
  const int slc = (lane & 7) ^ sr8;           // logical k-chunk to fetch
  const int srow = wave * 8 + sr8;            // row within 32-row stripe

  f32x4 acc[4][4];
#pragma unroll
  for (int i = 0; i < 4; i++)
#pragma unroll
    for (int j = 0; j < 4; j++) acc[i][j] = {0.f, 0.f, 0.f, 0.f};

  const u16* Ab = A + (size_t)bm * K;
  const u16* Wb = W + (size_t)bn * K;

  for (int kt = 0; kt < K; kt += 64) {
    __syncthreads();  // previous iteration's LDS reads complete
#pragma unroll
    for (int i = 0; i < 4; i++)
      gl2lds16(Ab + (size_t)(i * 32 + srow) * K + kt + slc * 8,
               &As[(i * 32 + wave * 8) * 64]);
#pragma unroll
    for (int i = 0; i < 4; i++)
      gl2lds16(Wb + (size_t)(i * 32 + srow) * K + kt + slc * 8,
               &Ws[(i * 32 + wave * 8) * 64]);
    __syncthreads();  // drains vmcnt (async loads) + LDS visible

#pragma unroll
    for (int ks = 0; ks < 2; ks++) {
      const int ch = ks * 4 + quad;  // logical chunk of this fragment
      s16x8 a[4], b[4];
#pragma unroll
      for (int t = 0; t < 4; t++)
        a[t] = *(const s16x8*)&As[(wr + t * 16 + l16) * 64 + ((ch ^ (l16 & 7)) << 3)];
#pragma unroll
      for (int t = 0; t < 4; t++)
        b[t] = *(const s16x8*)&Ws[(wc + t * 16 + l16) * 64 + ((ch ^ (l16 & 7)) << 3)];
#pragma unroll
      for (int i = 0; i < 4; i++)
#pragma unroll
        for (int j = 0; j < 4; j++)
          acc[i][j] = __builtin_amdgcn_mfma_f32_16x16x32_bf16(a[i], b[j], acc[i][j], 0, 0, 0);
    }
  }

  // epilogue: C/D layout row = quad*4 + reg, col = lane&15
#pragma unroll
  for (int j = 0; j < 4; j++) {
    const int col = bn + wc + j * 16 + l16;
    const float bv = bias[col];
#pragma unroll
    for (int i = 0; i < 4; i++) {
      const int row0 = bm + wr + i * 16 + quad * 4;
#pragma unroll
      for (int r = 0; r < 4; r++) {
        const float val = acc[i][j][r] + bv;
        if (OUT_F32)
          ((float*)p.C[z])[(size_t)(row0 + r) * N + col] = val;
        else
          ((u16*)p.C[z])[(size_t)(row0 + r) * N + col] = f2bf(val);
      }
    }
  }
}

// ---------------------------------------------------------------------------
// V transpose: Vp[B,S,D] (bf16) -> Vt[(b*16+h)*64 + d][s]
// ---------------------------------------------------------------------------
__global__ __launch_bounds__(256) void transpose_v(const u16* __restrict__ Vp,
                                                   u16* __restrict__ Vt) {
  __shared__ u16 t[64 * 72];
  const int tid = threadIdx.x;
  const int bh = blockIdx.y, b = bh >> 4, h = bh & 15;
  const int s0 = blockIdx.x * 64;
  const int r = tid >> 4, c4 = (tid & 15) * 4;
#pragma unroll
  for (int i = 0; i < 4; i++) {
    const int s = i * 16 + r;
    u16x4 v = *(const u16x4*)&Vp[(size_t)(b * S_LEN + s0 + s) * DMODEL + h * 64 + c4];
    *(u16x4*)&t[s * 72 + c4] = v;
  }
  __syncthreads();
#pragma unroll
  for (int i = 0; i < 4; i++) {
    const int d = i * 16 + r;
    u16x4 v;
    v.x = t[(c4 + 0) * 72 + d];
    v.y = t[(c4 + 1) * 72 + d];
    v.z = t[(c4 + 2) * 72 + d];
    v.w = t[(c4 + 3) * 72 + d];
    *(u16x4*)&Vt[(size_t)(bh * 64 + d) * S_LEN + s0 + c4] = v;
  }
}

// ---------------------------------------------------------------------------
// Flash attention R10: 512 threads = 8 waves, each wave owns 16 q-rows.
// Numerics identical to R8 (exp2f(sA*c), scalar f2bf packing). Grid (16,32);
// 48KB LDS -> ~2 blocks/CU, ~16 waves/CU (was 8 in R8).
// ---------------------------------------------------------------------------
__global__ __launch_bounds__(512, 2) void attn_kernel(const u16* __restrict__ Qp,
                                                      const u16* __restrict__ Kp,
                                                      const u16* __restrict__ Vt,
                                                      u16* __restrict__ AO) {
  __shared__ u16 Qs[128 * 64];   // [q][d]   16 KB, 8-chunk XOR swizzle
  __shared__ u16 Ks[128 * 64];   // [kv][d]  16 KB, 8-chunk XOR swizzle
  __shared__ u16 Vs[64 * 128];   // [d][kv]  16 KB, 16-chunk XOR swizzle

  const int tid = threadIdx.x;
  const int wave = tid >> 6, lane = tid & 63;
  const int quad = lane >> 4, l16 = lane & 15;
  const int bh = blockIdx.y, b = bh >> 4, h = bh & 15;
  const int s0 = blockIdx.x * 128;
  const float c = 0.03125f * LOG2E;  // d_model^-0.5 * log2(e)

  // staging indices (512 threads): K/Q rows tid>>3 (+0/64), chunk tid&7;
  // V rows tid>>4 (+0/32), chunk tid&15. XOR swizzle row-bit-stable.
  const int sr = tid >> 3, sc8 = tid & 7;
  const int sxor = (sc8 ^ (sr & 7)) << 3;
  const int vr = tid >> 4, vc = tid & 15;
  const int vxor = (vc ^ (vr & 15)) << 3;

  // ---- Q stage + fragments (16 rows per wave) ----
#pragma unroll
  for (int i = 0; i < 2; i++) {
    const int rr = i * 64 + sr;
    s16x8 qv = *(const s16x8*)(Qp + (size_t)(b * S_LEN + s0 + rr) * DMODEL + h * 64 + sc8 * 8);
    *(s16x8*)&Qs[rr * 64 + sxor] = qv;
  }
  __syncthreads();

  s16x8 aq[2];
#pragma unroll
  for (int ks = 0; ks < 2; ks++) {
    const int ch = ks * 4 + quad;
    aq[ks] = *(const s16x8*)&Qs[(wave * 16 + l16) * 64 + ((ch ^ (l16 & 7)) << 3)];
  }

  // ---- K/V register prefetch for kt=0 ----
  s16x8 kv[2], vv[2];
#pragma unroll
  for (int i = 0; i < 2; i++)
    kv[i] = *(const s16x8*)(Kp + (size_t)(b * S_LEN + i * 64 + sr) * DMODEL + h * 64 + sc8 * 8);
#pragma unroll
  for (int i = 0; i < 2; i++)
    vv[i] = *(const s16x8*)(Vt + (size_t)(bh * 64 + i * 32 + vr) * S_LEN + vc * 8);

  f32x4 o[4];
  float l_r = 0.f;
#pragma unroll
  for (int dt = 0; dt < 4; dt++) o[dt] = {0.f, 0.f, 0.f, 0.f};

  const f32x4 zf = {0.f, 0.f, 0.f, 0.f};

  for (int kt = 0; kt < S_LEN; kt += 128) {
    __syncthreads();
#pragma unroll
    for (int i = 0; i < 2; i++)
      *(s16x8*)&Ks[(i * 64 + sr) * 64 + sxor] = kv[i];
#pragma unroll
    for (int i = 0; i < 2; i++)
      *(s16x8*)&Vs[(i * 32 + vr) * 128 + vxor] = vv[i];
    __syncthreads();

    if (kt + 128 < S_LEN) {
      const int k2 = kt + 128;
#pragma unroll
      for (int i = 0; i < 2; i++)
        kv[i] = *(const s16x8*)(Kp + (size_t)(b * S_LEN + k2 + i * 64 + sr) * DMODEL + h * 64 + sc8 * 8);
#pragma unroll
      for (int i = 0; i < 2; i++)
        vv[i] = *(const s16x8*)(Vt + (size_t)(bh * 64 + i * 32 + vr) * S_LEN + k2 + vc * 8);
    }

#pragma unroll
    for (int kvt = 0; kvt < 8; kvt++) {
      const int krow = kvt * 16 + l16;
      s16x8 ak0 = *(const s16x8*)&Ks[krow * 64 + (((0 + quad) ^ (l16 & 7)) << 3)];
      s16x8 ak1 = *(const s16x8*)&Ks[krow * 64 + (((4 + quad) ^ (l16 & 7)) << 3)];
      f32x4 sA;
      sA = __builtin_amdgcn_mfma_f32_16x16x32_bf16(ak0, aq[0], zf, 0, 0, 0);
      sA = __builtin_amdgcn_mfma_f32_16x16x32_bf16(ak1, aq[1], sA, 0, 0, 0);

      s16x4 pf;
      float rs = 0.f;
#pragma unroll
      for (int r = 0; r < 4; r++) {
        const float p0 = exp2f(sA[r] * c);
        rs += p0;
        pf[r] = (short)f2bf(p0);
      }
      l_r += rs;

      const int ch = kvt * 2 + (quad >> 1);
#pragma unroll
      for (int dt = 0; dt < 4; dt++) {
        const int row = dt * 16 + l16;
        s16x4 bv = *(const s16x4*)&Vs[row * 128 + ((ch ^ l16) << 3) + (quad & 1) * 4];
        o[dt] = __builtin_amdgcn_mfma_f32_16x16x16bf16_1k(pf, bv, o[dt], 0, 0, 0);
      }
    }
  }

  // denominator: lane holds partial for q = l16 over its quad's kv share
  l_r += __shfl_xor(l_r, 16);
  l_r += __shfl_xor(l_r, 32);
#pragma unroll
  for (int r = 0; r < 4; r++) {
    const float linv = 1.f / __shfl(l_r, quad * 4 + r);
    const int row = s0 + wave * 16 + quad * 4 + r;
#pragma unroll
    for (int dt = 0; dt < 4; dt++)
      AO[(size_t)(b * S_LEN + row) * DMODEL + h * 64 + dt * 16 + l16] =
          f2bf(o[dt][r] * linv);
  }
}

// ---------------------------------------------------------------------------
extern "C" void kernel_launch(void* const* d_in, const int* in_sizes, int n_in,
                              void* d_out, int out_size, void* d_ws, size_t ws_size,
                              hipStream_t stream) {
  const float* query = (const float*)d_in[0];
  const float* key_  = (const float*)d_in[1];
  const float* value = (const float*)d_in[2];
  const float* W_q = (const float*)d_in[3];
  const float* b_q = (const float*)d_in[4];
  const float* W_k = (const float*)d_in[5];
  const float* b_k = (const float*)d_in[6];
  const float* W_v = (const float*)d_in[7];
  const float* b_v = (const float*)d_in[8];
  const float* W_o = (const float*)d_in[9];
  const float* b_o = (const float*)d_in[10];
  float* out = (float*)d_out;

  const int M = 2 * S_LEN;  // 4096
  const int N = DMODEL, K = DMODEL;
  const size_t WSZ = (size_t)DMODEL * DMODEL;   // 1,048,576
  const size_t SZ  = (size_t)M * DMODEL;        // 4,194,304

  u16* Wqb = (u16*)d_ws;         // 4 bf16 weights
  u16* Wkb = Wqb + WSZ;
  u16* Wvb = Wkb + WSZ;
  u16* Wob = Wvb + WSZ;
  u16* Qa  = Wob + WSZ;          // bf16 inputs (dead after QKV GEMM)
  u16* Ka  = Qa + SZ;
  u16* Va  = Ka + SZ;
  u16* Qp  = Va + SZ;            // projections
  u16* Kp  = Qp + SZ;
  u16* Vp  = Kp + SZ;
  u16* Vt  = Qa;                 // aliases Qa (dead): [B,H,Dh,S]
  u16* AO  = Qp;                 // aliases Qp (per-block disjoint read->write)

  Cvt7 cw;
  cw.s[0] = W_q;   cw.d[0] = Wqb; cw.n[0] = (int)WSZ;
  cw.s[1] = W_k;   cw.d[1] = Wkb; cw.n[1] = (int)WSZ;
  cw.s[2] = W_v;   cw.d[2] = Wvb; cw.n[2] = (int)WSZ;
  cw.s[3] = W_o;   cw.d[3] = Wob; cw.n[3] = (int)WSZ;
  cw.s[4] = query; cw.d[4] = Qa;  cw.n[4] = (int)SZ;
  cw.s[5] = key_;  cw.d[5] = Ka;  cw.n[5] = (int)SZ;
  cw.s[6] = value; cw.d[6] = Va;  cw.n[6] = (int)SZ;
  cvt7<<<dim3((int)(SZ / 2048), 7), 256, 0, stream>>>(cw);

  GemmBatch p1;
  p1.A[0] = Qa; p1.W[0] = Wqb; p1.Bv[0] = b_q; p1.C[0] = Qp;
  p1.A[1] = Ka; p1.W[1] = Wkb; p1.Bv[1] = b_k; p1.C[1] = Kp;
  p1.A[2] = Va; p1.W[2] = Wvb; p1.Bv[2] = b_v; p1.C[2] = Vp;
  gemm_bt<false><<<dim3(N / 128, M / 128, 3), 256, 0, stream>>>(p1, M, N, K);

  transpose_v<<<dim3(S_LEN / 64, 32), 256, 0, stream>>>(Vp, Vt);

  attn_kernel<<<dim3(S_LEN / 128, 32), 512, 0, stream>>>(Qp, Kp, Vt, AO);

  GemmBatch p2;
  p2.A[0] = AO; p2.W[0] = Wob; p2.Bv[0] = b_o; p2.C[0] = out;
  p2.A[1] = AO; p2.W[1] = Wob; p2.Bv[1] = b_o; p2.C[1] = out;
  p2.A[2] = AO; p2.W[2] = Wob; p2.Bv[2] = b_o; p2.C[2] = out;
  gemm_bt<true><<<dim3(N / 128, M / 128, 1), 256, 0, stream>>>(p2, M, N, K);
}

// Round 3
// 241.156 us; speedup vs baseline: 1.0843x; 1.0578x over previous
//
#include <hip/hip_runtime.h>
#include <stdint.h>

// MultiHeadAttention: B=2, S=2048, D=1024, H=16, Dh=64. fp32 in/out, bf16 MFMA inside.
// R11: GEMM-side round (attn untouched from R10).
//  - gemm_bt templated <BM,BN,OUT_F32,VT>: O-projection moves 128x128 (256 blocks,
//    1 block/CU, 1 wave/SIMD -- latency-crippled) -> 64x64 (1024 blocks, 4/CU,
//    16 waves/CU).
//  - V-GEMM (z=2) epilogue fuses the V transpose: acc -> LDS [col][row] tile
//    (stride 136 u16, 16B-aligned) -> coalesced Vt writes. transpose_v kernel
//    deleted (saves 16MB+16MB transpose traffic + 8MB Vp writes + a launch).
//    Values go through the identical f2bf(acc+bias) path => bit-exact vs R10.

typedef unsigned short u16;
typedef short s16x8 __attribute__((ext_vector_type(8)));   // 8 bf16 (4 VGPR)
typedef short s16x4 __attribute__((ext_vector_type(4)));   // 4 bf16 (2 VGPR)
typedef float f32x4 __attribute__((ext_vector_type(4)));
typedef u16 u16x4 __attribute__((ext_vector_type(4)));

#define S_LEN 2048
#define DMODEL 1024
#define LOG2E 1.44269504088896340736f

__device__ __forceinline__ u16 f2bf(float f) {
  union { float f; uint32_t u; } v; v.f = f;
  return (u16)((v.u + 0x8000u) >> 16);
}

__device__ __forceinline__ s16x8 ld8f(const float* s) {  // 8 fp32 -> 8 bf16
  f32x4 a = *(const f32x4*)s;
  f32x4 b = *(const f32x4*)(s + 4);
  s16x8 r;
  r[0] = (short)f2bf(a[0]); r[1] = (short)f2bf(a[1]);
  r[2] = (short)f2bf(a[2]); r[3] = (short)f2bf(a[3]);
  r[4] = (short)f2bf(b[0]); r[5] = (short)f2bf(b[1]);
  r[6] = (short)f2bf(b[2]); r[7] = (short)f2bf(b[3]);
  return r;
}

// async global->LDS, 16B/lane; HW scatters lane i to ldsbase + i*16
__device__ __forceinline__ void gl2lds16(const u16* g, u16* l) {
  __builtin_amdgcn_global_load_lds(
      (const __attribute__((address_space(1))) uint32_t*)g,
      (__attribute__((address_space(3))) uint32_t*)l, 16, 0, 0);
}

// ---------------------------------------------------------------------------
// fp32 -> bf16 conversion: 4 weights (1M elem) + 3 activations (4.19M elem).
// ---------------------------------------------------------------------------
struct Cvt7 { const float* s[7]; u16* d[7]; int n[7]; };

__global__ __launch_bounds__(256) void cvt7(Cvt7 p) {
  const int z = blockIdx.y;
  const int idx = blockIdx.x * 256 + threadIdx.x;
  if (idx * 8 < p.n[z])
    *(s16x8*)(p.d[z] + (size_t)idx * 8) = ld8f(p.s[z] + (size_t)idx * 8);
}

// ---------------------------------------------------------------------------
// GEMM: C[M,N] = A[M,K] @ W[N,K]^T + bias[N]; A,W bf16, bias fp32.
// Template: BM x BN tile (BK=64 fixed), 4 waves as 2x2 of (BM/2 x BN/2).
// OUT_F32: fp32 C (O projection). VT: z==2 writes transposed bf16 to p.vt
// (V path) instead of C -- epilogue routes acc through an LDS [BN][TS] tile.
// ---------------------------------------------------------------------------
struct GemmBatch {
  const u16* A[3]; const u16* W[3]; const float* Bv[3]; void* C[3];
  u16* vt;   // VT destination: Vt[(b*16+h)*64+dh][s], row stride S_LEN
};

template <int BM, int BN, bool OUT_F32, bool VT>
__global__ __launch_bounds__(256) void gemm_bt(GemmBatch p, int M, int N, int K) {
  static_assert(!VT || (BM == 128 && BN == 128), "VT epilogue assumes 128x128");
  constexpr int MI = BM / 32, NJ = BN / 32;   // fragment repeats per wave
  constexpr int TS = BM + 8;                  // VT transpose stride (u16), 16B-aligned
  constexpr int AB = BM * 64 + BN * 64;
  constexpr int TB = VT ? BN * TS : 0;
  constexpr int SM = AB > TB ? AB : TB;
  __shared__ u16 smem[SM];
  u16* const As = smem;
  u16* const Ws = smem + BM * 64;

  const int z = blockIdx.z;
  const u16* __restrict__ A      = p.A[z];
  const u16* __restrict__ W      = p.W[z];
  const float* __restrict__ bias = p.Bv[z];

  const int tid = threadIdx.x;
  const int wave = tid >> 6, lane = tid & 63;
  const int quad = lane >> 4, l16 = lane & 15;
  const int bm = blockIdx.y * BM, bn = blockIdx.x * BN;
  const int wr = (wave >> 1) * (BM / 2), wc = (wave & 1) * (BN / 2);
  const int sr8 = lane >> 3;
  const int slc = (lane & 7) ^ sr8;           // logical k-chunk to fetch
  const int srow = wave * 8 + sr8;            // row within 32-row stripe

  f32x4 acc[MI][NJ];
#pragma unroll
  for (int i = 0; i < MI; i++)
#pragma unroll
    for (int j = 0; j < NJ; j++) acc[i][j] = {0.f, 0.f, 0.f, 0.f};

  const u16* Ab = A + (size_t)bm * K;
  const u16* Wb = W + (size_t)bn * K;

  for (int kt = 0; kt < K; kt += 64) {
    __syncthreads();  // previous iteration's LDS reads complete
#pragma unroll
    for (int i = 0; i < MI; i++)
      gl2lds16(Ab + (size_t)(i * 32 + srow) * K + kt + slc * 8,
               &As[(i * 32 + wave * 8) * 64]);
#pragma unroll
    for (int i = 0; i < NJ; i++)
      gl2lds16(Wb + (size_t)(i * 32 + srow) * K + kt + slc * 8,
               &Ws[(i * 32 + wave * 8) * 64]);
    __syncthreads();  // drains vmcnt (async loads) + LDS visible

#pragma unroll
    for (int ks = 0; ks < 2; ks++) {
      const int ch = ks * 4 + quad;  // logical chunk of this fragment
      s16x8 a[MI], b[NJ];
#pragma unroll
      for (int t = 0; t < MI; t++)
        a[t] = *(const s16x8*)&As[(wr + t * 16 + l16) * 64 + ((ch ^ (l16 & 7)) << 3)];
#pragma unroll
      for (int t = 0; t < NJ; t++)
        b[t] = *(const s16x8*)&Ws[(wc + t * 16 + l16) * 64 + ((ch ^ (l16 & 7)) << 3)];
#pragma unroll
      for (int i = 0; i < MI; i++)
#pragma unroll
        for (int j = 0; j < NJ; j++)
          acc[i][j] = __builtin_amdgcn_mfma_f32_16x16x32_bf16(a[i], b[j], acc[i][j], 0, 0, 0);
    }
  }

  if (VT && z == 2) {
    // ---- fused V transpose: acc -> LDS [col][row] -> Vt[d-row][s] ----
    __syncthreads();               // all waves done reading As/Ws
    u16* const T = smem;           // [BN][TS]
#pragma unroll
    for (int j = 0; j < NJ; j++) {
      const int c = wc + j * 16 + l16;
      const float bv = bias[bn + c];
#pragma unroll
      for (int i = 0; i < MI; i++) {
        const int r0 = wr + i * 16 + quad * 4;
        u16x4 t4;
#pragma unroll
        for (int r = 0; r < 4; r++) t4[r] = f2bf(acc[i][j][r] + bv);
        *(u16x4*)&T[c * TS + r0] = t4;
      }
    }
    __syncthreads();
    // thread -> (c = tid>>1, half = tid&1): 64 contiguous s per thread
    const int c = tid >> 1, half = tid & 1;
    const int b_ = bm >> 11;                 // batch (2048 rows each, 128 | 2048)
    const int sb = (bm & 2047) + half * 64;  // s within batch
    u16* dst = p.vt + (size_t)(b_ * 1024 + bn + c) * S_LEN + sb;
    const u16* srcT = &T[c * TS + half * 64];
#pragma unroll
    for (int k = 0; k < 8; k++)
      *(s16x8*)(dst + k * 8) = *(const s16x8*)(srcT + k * 8);
  } else {
    // epilogue: C/D layout row = quad*4 + reg, col = lane&15
#pragma unroll
    for (int j = 0; j < NJ; j++) {
      const int col = bn + wc + j * 16 + l16;
      const float bv = bias[col];
#pragma unroll
      for (int i = 0; i < MI; i++) {
        const int row0 = bm + wr + i * 16 + quad * 4;
#pragma unroll
        for (int r = 0; r < 4; r++) {
          const float val = acc[i][j][r] + bv;
          if (OUT_F32)
            ((float*)p.C[z])[(size_t)(row0 + r) * N + col] = val;
          else
            ((u16*)p.C[z])[(size_t)(row0 + r) * N + col] = f2bf(val);
        }
      }
    }
  }
}

// ---------------------------------------------------------------------------
// Flash attention (R10, unchanged): 512 threads = 8 waves x 16 q-rows.
// Grid (16,32); 48KB LDS -> 2 blocks/CU, ~16 waves/CU.
// ---------------------------------------------------------------------------
__global__ __launch_bounds__(512, 2) void attn_kernel(const u16* __restrict__ Qp,
                                                      const u16* __restrict__ Kp,
                                                      const u16* __restrict__ Vt,
                                                      u16* __restrict__ AO) {
  __shared__ u16 Qs[128 * 64];   // [q][d]   16 KB, 8-chunk XOR swizzle
  __shared__ u16 Ks[128 * 64];   // [kv][d]  16 KB, 8-chunk XOR swizzle
  __shared__ u16 Vs[64 * 128];   // [d][kv]  16 KB, 16-chunk XOR swizzle

  const int tid = threadIdx.x;
  const int wave = tid >> 6, lane = tid & 63;
  const int quad = lane >> 4, l16 = lane & 15;
  const int bh = blockIdx.y, b = bh >> 4, h = bh & 15;
  const int s0 = blockIdx.x * 128;
  const float c = 0.03125f * LOG2E;  // d_model^-0.5 * log2(e)

  const int sr = tid >> 3, sc8 = tid & 7;
  const int sxor = (sc8 ^ (sr & 7)) << 3;
  const int vr = tid >> 4, vc = tid & 15;
  const int vxor = (vc ^ (vr & 15)) << 3;

  // ---- Q stage + fragments (16 rows per wave) ----
#pragma unroll
  for (int i = 0; i < 2; i++) {
    const int rr = i * 64 + sr;
    s16x8 qv = *(const s16x8*)(Qp + (size_t)(b * S_LEN + s0 + rr) * DMODEL + h * 64 + sc8 * 8);
    *(s16x8*)&Qs[rr * 64 + sxor] = qv;
  }
  __syncthreads();

  s16x8 aq[2];
#pragma unroll
  for (int ks = 0; ks < 2; ks++) {
    const int ch = ks * 4 + quad;
    aq[ks] = *(const s16x8*)&Qs[(wave * 16 + l16) * 64 + ((ch ^ (l16 & 7)) << 3)];
  }

  // ---- K/V register prefetch for kt=0 ----
  s16x8 kv[2], vv[2];
#pragma unroll
  for (int i = 0; i < 2; i++)
    kv[i] = *(const s16x8*)(Kp + (size_t)(b * S_LEN + i * 64 + sr) * DMODEL + h * 64 + sc8 * 8);
#pragma unroll
  for (int i = 0; i < 2; i++)
    vv[i] = *(const s16x8*)(Vt + (size_t)(bh * 64 + i * 32 + vr) * S_LEN + vc * 8);

  f32x4 o[4];
  float l_r = 0.f;
#pragma unroll
  for (int dt = 0; dt < 4; dt++) o[dt] = {0.f, 0.f, 0.f, 0.f};

  const f32x4 zf = {0.f, 0.f, 0.f, 0.f};

  for (int kt = 0; kt < S_LEN; kt += 128) {
    __syncthreads();
#pragma unroll
    for (int i = 0; i < 2; i++)
      *(s16x8*)&Ks[(i * 64 + sr) * 64 + sxor] = kv[i];
#pragma unroll
    for (int i = 0; i < 2; i++)
      *(s16x8*)&Vs[(i * 32 + vr) * 128 + vxor] = vv[i];
    __syncthreads();

    if (kt + 128 < S_LEN) {
      const int k2 = kt + 128;
#pragma unroll
      for (int i = 0; i < 2; i++)
        kv[i] = *(const s16x8*)(Kp + (size_t)(b * S_LEN + k2 + i * 64 + sr) * DMODEL + h * 64 + sc8 * 8);
#pragma unroll
      for (int i = 0; i < 2; i++)
        vv[i] = *(const s16x8*)(Vt + (size_t)(bh * 64 + i * 32 + vr) * S_LEN + k2 + vc * 8);
    }

#pragma unroll
    for (int kvt = 0; kvt < 8; kvt++) {
      const int krow = kvt * 16 + l16;
      s16x8 ak0 = *(const s16x8*)&Ks[krow * 64 + (((0 + quad) ^ (l16 & 7)) << 3)];
      s16x8 ak1 = *(const s16x8*)&Ks[krow * 64 + (((4 + quad) ^ (l16 & 7)) << 3)];
      f32x4 sA;
      sA = __builtin_amdgcn_mfma_f32_16x16x32_bf16(ak0, aq[0], zf, 0, 0, 0);
      sA = __builtin_amdgcn_mfma_f32_16x16x32_bf16(ak1, aq[1], sA, 0, 0, 0);

      s16x4 pf;
      float rs = 0.f;
#pragma unroll
      for (int r = 0; r < 4; r++) {
        const float p0 = exp2f(sA[r] * c);
        rs += p0;
        pf[r] = (short)f2bf(p0);
      }
      l_r += rs;

      const int ch = kvt * 2 + (quad >> 1);
#pragma unroll
      for (int dt = 0; dt < 4; dt++) {
        const int row = dt * 16 + l16;
        s16x4 bv = *(const s16x4*)&Vs[row * 128 + ((ch ^ l16) << 3) + (quad & 1) * 4];
        o[dt] = __builtin_amdgcn_mfma_f32_16x16x16bf16_1k(pf, bv, o[dt], 0, 0, 0);
      }
    }
  }

  l_r += __shfl_xor(l_r, 16);
  l_r += __shfl_xor(l_r, 32);
#pragma unroll
  for (int r = 0; r < 4; r++) {
    const float linv = 1.f / __shfl(l_r, quad * 4 + r);
    const int row = s0 + wave * 16 + quad * 4 + r;
#pragma unroll
    for (int dt = 0; dt < 4; dt++)
      AO[(size_t)(b * S_LEN + row) * DMODEL + h * 64 + dt * 16 + l16] =
          f2bf(o[dt][r] * linv);
  }
}

// ---------------------------------------------------------------------------
extern "C" void kernel_launch(void* const* d_in, const int* in_sizes, int n_in,
                              void* d_out, int out_size, void* d_ws, size_t ws_size,
                              hipStream_t stream) {
  const float* query = (const float*)d_in[0];
  const float* key_  = (const float*)d_in[1];
  const float* value = (const float*)d_in[2];
  const float* W_q = (const float*)d_in[3];
  const float* b_q = (const float*)d_in[4];
  const float* W_k = (const float*)d_in[5];
  const float* b_k = (const float*)d_in[6];
  const float* W_v = (const float*)d_in[7];
  const float* b_v = (const float*)d_in[8];
  const float* W_o = (const float*)d_in[9];
  const float* b_o = (const float*)d_in[10];
  float* out = (float*)d_out;

  const int M = 2 * S_LEN;  // 4096
  const int N = DMODEL, K = DMODEL;
  const size_t WSZ = (size_t)DMODEL * DMODEL;   // 1,048,576
  const size_t SZ  = (size_t)M * DMODEL;        // 4,194,304

  u16* Wqb = (u16*)d_ws;         // 4 bf16 weights
  u16* Wkb = Wqb + WSZ;
  u16* Wvb = Wkb + WSZ;
  u16* Wob = Wvb + WSZ;
  u16* Qa  = Wob + WSZ;          // bf16 inputs (dead after QKV GEMM)
  u16* Ka  = Qa + SZ;
  u16* Va  = Ka + SZ;
  u16* Qp  = Va + SZ;            // projections
  u16* Kp  = Qp + SZ;
  u16* Vt  = Kp + SZ;            // [B,H,Dh,S] -- written directly by V-GEMM (VT path)
  u16* AO  = Qp;                 // aliases Qp (per-block disjoint read->write)

  Cvt7 cw;
  cw.s[0] = W_q;   cw.d[0] = Wqb; cw.n[0] = (int)WSZ;
  cw.s[1] = W_k;   cw.d[1] = Wkb; cw.n[1] = (int)WSZ;
  cw.s[2] = W_v;   cw.d[2] = Wvb; cw.n[2] = (int)WSZ;
  cw.s[3] = W_o;   cw.d[3] = Wob; cw.n[3] = (int)WSZ;
  cw.s[4] = query; cw.d[4] = Qa;  cw.n[4] = (int)SZ;
  cw.s[5] = key_;  cw.d[5] = Ka;  cw.n[5] = (int)SZ;
  cw.s[6] = value; cw.d[6] = Va;  cw.n[6] = (int)SZ;
  cvt7<<<dim3((int)(SZ / 2048), 7), 256, 0, stream>>>(cw);

  GemmBatch p1;
  p1.A[0] = Qa; p1.W[0] = Wqb; p1.Bv[0] = b_q; p1.C[0] = Qp;
  p1.A[1] = Ka; p1.W[1] = Wkb; p1.Bv[1] = b_k; p1.C[1] = Kp;
  p1.A[2] = Va; p1.W[2] = Wvb; p1.Bv[2] = b_v; p1.C[2] = Vt;  // unused (VT path)
  p1.vt = Vt;
  gemm_bt<128, 128, false, true><<<dim3(N / 128, M / 128, 3), 256, 0, stream>>>(p1, M, N, K);

  attn_kernel<<<dim3(S_LEN / 128, 32), 512, 0, stream>>>(Qp, Kp, Vt, AO);

  GemmBatch p2;
  p2.A[0] = AO; p2.W[0] = Wob; p2.Bv[0] = b_o; p2.C[0] = out;
  p2.A[1] = AO; p2.W[1] = Wob; p2.Bv[1] = b_o; p2.C[1] = out;
  p2.A[2] = AO; p2.W[2] = Wob; p2.Bv[2] = b_o; p2.C[2] = out;
  p2.vt = nullptr;
  gemm_bt<64, 64, true, false><<<dim3(N / 64, M / 64, 1), 256, 0, stream>>>(p2, M, N, K);
}

// Round 4
// 229.273 us; speedup vs baseline: 1.1405x; 1.0518x over previous
//
#include <hip/hip_runtime.h>
#include <stdint.h>

// MultiHeadAttention: B=2, S=2048, D=1024, H=16, Dh=64. fp32 in/out, bf16 MFMA inside.
// R12: attn VALU-cut round (GEMM structure unchanged from R11).
//  - Score scale folded into Q-GEMM epilogue (fp32, pre-round): isolates R9's (b).
//  - exp2 via __builtin_amdgcn_exp2f (raw v_exp_f32, no libm fixup; |x|<~40 safe).
//  - P-packing via v_perm_b32: bit-identical to scalar f2bf path, ~1/2 the ops.
// R11 carried: fused V-transpose in V-GEMM epilogue, 64x64 O-GEMM (16 waves/CU).

typedef unsigned short u16;
typedef short s16x8 __attribute__((ext_vector_type(8)));   // 8 bf16 (4 VGPR)
typedef short s16x4 __attribute__((ext_vector_type(4)));   // 4 bf16 (2 VGPR)
typedef float f32x4 __attribute__((ext_vector_type(4)));
typedef u16 u16x4 __attribute__((ext_vector_type(4)));

#define S_LEN 2048
#define DMODEL 1024
#define LOG2E 1.44269504088896340736f

__device__ __forceinline__ u16 f2bf(float f) {
  union { float f; uint32_t u; } v; v.f = f;
  return (u16)((v.u + 0x8000u) >> 16);
}

__device__ __forceinline__ s16x8 ld8f(const float* s) {  // 8 fp32 -> 8 bf16
  f32x4 a = *(const f32x4*)s;
  f32x4 b = *(const f32x4*)(s + 4);
  s16x8 r;
  r[0] = (short)f2bf(a[0]); r[1] = (short)f2bf(a[1]);
  r[2] = (short)f2bf(a[2]); r[3] = (short)f2bf(a[3]);
  r[4] = (short)f2bf(b[0]); r[5] = (short)f2bf(b[1]);
  r[6] = (short)f2bf(b[2]); r[7] = (short)f2bf(b[3]);
  return r;
}

// async global->LDS, 16B/lane; HW scatters lane i to ldsbase + i*16
__device__ __forceinline__ void gl2lds16(const u16* g, u16* l) {
  __builtin_amdgcn_global_load_lds(
      (const __attribute__((address_space(1))) uint32_t*)g,
      (__attribute__((address_space(3))) uint32_t*)l, 16, 0, 0);
}

// ---------------------------------------------------------------------------
// fp32 -> bf16 conversion: 4 weights (1M elem) + 3 activations (4.19M elem).
// ---------------------------------------------------------------------------
struct Cvt7 { const float* s[7]; u16* d[7]; int n[7]; };

__global__ __launch_bounds__(256) void cvt7(Cvt7 p) {
  const int z = blockIdx.y;
  const int idx = blockIdx.x * 256 + threadIdx.x;
  if (idx * 8 < p.n[z])
    *(s16x8*)(p.d[z] + (size_t)idx * 8) = ld8f(p.s[z] + (size_t)idx * 8);
}

// ---------------------------------------------------------------------------
// GEMM: C[M,N] = (A[M,K] @ W[N,K]^T + bias[N]) * scl; A,W bf16, bias fp32.
// scl=1.0 for all but the Q projection (score scale folded in, fp32 pre-round).
// Template: BM x BN tile (BK=64 fixed), 4 waves as 2x2 of (BM/2 x BN/2).
// OUT_F32: fp32 C (O projection). VT: z==2 writes transposed bf16 to p.vt.
// ---------------------------------------------------------------------------
struct GemmBatch {
  const u16* A[3]; const u16* W[3]; const float* Bv[3]; void* C[3];
  u16* vt;       // VT destination: Vt[(b*16+h)*64+dh][s], row stride S_LEN
  float scl[3];  // epilogue scale (fp32, applied before f2bf round)
};

template <int BM, int BN, bool OUT_F32, bool VT>
__global__ __launch_bounds__(256) void gemm_bt(GemmBatch p, int M, int N, int K) {
  static_assert(!VT || (BM == 128 && BN == 128), "VT epilogue assumes 128x128");
  constexpr int MI = BM / 32, NJ = BN / 32;   // fragment repeats per wave
  constexpr int TS = BM + 8;                  // VT transpose stride (u16), 16B-aligned
  constexpr int AB = BM * 64 + BN * 64;
  constexpr int TB = VT ? BN * TS : 0;
  constexpr int SM = AB > TB ? AB : TB;
  __shared__ u16 smem[SM];
  u16* const As = smem;
  u16* const Ws = smem + BM * 64;

  const int z = blockIdx.z;
  const u16* __restrict__ A      = p.A[z];
  const u16* __restrict__ W      = p.W[z];
  const float* __restrict__ bias = p.Bv[z];
  const float scl = p.scl[z];

  const int tid = threadIdx.x;
  const int wave = tid >> 6, lane = tid & 63;
  const int quad = lane >> 4, l16 = lane & 15;
  const int bm = blockIdx.y * BM, bn = blockIdx.x * BN;
  const int wr = (wave >> 1) * (BM / 2), wc = (wave & 1) * (BN / 2);
  const int sr8 = lane >> 3;
  const int slc = (lane & 7) ^ sr8;           // logical k-chunk to fetch
  const int srow = wave * 8 + sr8;            // row within 32-row stripe

  f32x4 acc[MI][NJ];
#pragma unroll
  for (int i = 0; i < MI; i++)
#pragma unroll
    for (int j = 0; j < NJ; j++) acc[i][j] = {0.f, 0.f, 0.f, 0.f};

  const u16* Ab = A + (size_t)bm * K;
  const u16* Wb = W + (size_t)bn * K;

  for (int kt = 0; kt < K; kt += 64) {
    __syncthreads();  // previous iteration's LDS reads complete
#pragma unroll
    for (int i = 0; i < MI; i++)
      gl2lds16(Ab + (size_t)(i * 32 + srow) * K + kt + slc * 8,
               &As[(i * 32 + wave * 8) * 64]);
#pragma unroll
    for (int i = 0; i < NJ; i++)
      gl2lds16(Wb + (size_t)(i * 32 + srow) * K + kt + slc * 8,
               &Ws[(i * 32 + wave * 8) * 64]);
    __syncthreads();  // drains vmcnt (async loads) + LDS visible

#pragma unroll
    for (int ks = 0; ks < 2; ks++) {
      const int ch = ks * 4 + quad;  // logical chunk of this fragment
      s16x8 a[MI], b[NJ];
#pragma unroll
      for (int t = 0; t < MI; t++)
        a[t] = *(const s16x8*)&As[(wr + t * 16 + l16) * 64 + ((ch ^ (l16 & 7)) << 3)];
#pragma unroll
      for (int t = 0; t < NJ; t++)
        b[t] = *(const s16x8*)&Ws[(wc + t * 16 + l16) * 64 + ((ch ^ (l16 & 7)) << 3)];
#pragma unroll
      for (int i = 0; i < MI; i++)
#pragma unroll
        for (int j = 0; j < NJ; j++)
          acc[i][j] = __builtin_amdgcn_mfma_f32_16x16x32_bf16(a[i], b[j], acc[i][j], 0, 0, 0);
    }
  }

  if (VT && z == 2) {
    // ---- fused V transpose: acc -> LDS [col][row] -> Vt[d-row][s] ----
    __syncthreads();               // all waves done reading As/Ws
    u16* const T = smem;           // [BN][TS]
#pragma unroll
    for (int j = 0; j < NJ; j++) {
      const int c = wc + j * 16 + l16;
      const float bv = bias[bn + c];
#pragma unroll
      for (int i = 0; i < MI; i++) {
        const int r0 = wr + i * 16 + quad * 4;
        u16x4 t4;
#pragma unroll
        for (int r = 0; r < 4; r++) t4[r] = f2bf((acc[i][j][r] + bv) * scl);
        *(u16x4*)&T[c * TS + r0] = t4;
      }
    }
    __syncthreads();
    // thread -> (c = tid>>1, half = tid&1): 64 contiguous s per thread
    const int c = tid >> 1, half = tid & 1;
    const int b_ = bm >> 11;                 // batch (2048 rows each, 128 | 2048)
    const int sb = (bm & 2047) + half * 64;  // s within batch
    u16* dst = p.vt + (size_t)(b_ * 1024 + bn + c) * S_LEN + sb;
    const u16* srcT = &T[c * TS + half * 64];
#pragma unroll
    for (int k = 0; k < 8; k++)
      *(s16x8*)(dst + k * 8) = *(const s16x8*)(srcT + k * 8);
  } else {
    // epilogue: C/D layout row = quad*4 + reg, col = lane&15
#pragma unroll
    for (int j = 0; j < NJ; j++) {
      const int col = bn + wc + j * 16 + l16;
      const float bv = bias[col];
#pragma unroll
      for (int i = 0; i < MI; i++) {
        const int row0 = bm + wr + i * 16 + quad * 4;
#pragma unroll
        for (int r = 0; r < 4; r++) {
          const float val = (acc[i][j][r] + bv) * scl;
          if (OUT_F32)
            ((float*)p.C[z])[(size_t)(row0 + r) * N + col] = val;
          else
            ((u16*)p.C[z])[(size_t)(row0 + r) * N + col] = f2bf(val);
        }
      }
    }
  }
}

// ---------------------------------------------------------------------------
// Flash attention R12: 512 threads = 8 waves x 16 q-rows. Q pre-scaled by
// d^-0.5*log2e (in Q-GEMM epilogue), so softmax is exp2(sA) directly.
// exp2 = raw v_exp_f32; P-pack = v_perm_b32 (bit-identical to f2bf).
// Grid (16,32); 48KB LDS -> 2 blocks/CU, ~16 waves/CU.
// ---------------------------------------------------------------------------
__global__ __launch_bounds__(512, 2) void attn_kernel(const u16* __restrict__ Qp,
                                                      const u16* __restrict__ Kp,
                                                      const u16* __restrict__ Vt,
                                                      u16* __restrict__ AO) {
  __shared__ u16 Qs[128 * 64];   // [q][d]   16 KB, 8-chunk XOR swizzle
  __shared__ u16 Ks[128 * 64];   // [kv][d]  16 KB, 8-chunk XOR swizzle
  __shared__ u16 Vs[64 * 128];   // [d][kv]  16 KB, 16-chunk XOR swizzle

  const int tid = threadIdx.x;
  const int wave = tid >> 6, lane = tid & 63;
  const int quad = lane >> 4, l16 = lane & 15;
  const int bh = blockIdx.y, b = bh >> 4, h = bh & 15;
  const int s0 = blockIdx.x * 128;

  const int sr = tid >> 3, sc8 = tid & 7;
  const int sxor = (sc8 ^ (sr & 7)) << 3;
  const int vr = tid >> 4, vc = tid & 15;
  const int vxor = (vc ^ (vr & 15)) << 3;

  // ---- Q stage + fragments (16 rows per wave) ----
#pragma unroll
  for (int i = 0; i < 2; i++) {
    const int rr = i * 64 + sr;
    s16x8 qv = *(const s16x8*)(Qp + (size_t)(b * S_LEN + s0 + rr) * DMODEL + h * 64 + sc8 * 8);
    *(s16x8*)&Qs[rr * 64 + sxor] = qv;
  }
  __syncthreads();

  s16x8 aq[2];
#pragma unroll
  for (int ks = 0; ks < 2; ks++) {
    const int ch = ks * 4 + quad;
    aq[ks] = *(const s16x8*)&Qs[(wave * 16 + l16) * 64 + ((ch ^ (l16 & 7)) << 3)];
  }

  // ---- K/V register prefetch for kt=0 ----
  s16x8 kv[2], vv[2];
#pragma unroll
  for (int i = 0; i < 2; i++)
    kv[i] = *(const s16x8*)(Kp + (size_t)(b * S_LEN + i * 64 + sr) * DMODEL + h * 64 + sc8 * 8);
#pragma unroll
  for (int i = 0; i < 2; i++)
    vv[i] = *(const s16x8*)(Vt + (size_t)(bh * 64 + i * 32 + vr) * S_LEN + vc * 8);

  f32x4 o[4];
  float l_r = 0.f;
#pragma unroll
  for (int dt = 0; dt < 4; dt++) o[dt] = {0.f, 0.f, 0.f, 0.f};

  const f32x4 zf = {0.f, 0.f, 0.f, 0.f};

  for (int kt = 0; kt < S_LEN; kt += 128) {
    __syncthreads();
#pragma unroll
    for (int i = 0; i < 2; i++)
      *(s16x8*)&Ks[(i * 64 + sr) * 64 + sxor] = kv[i];
#pragma unroll
    for (int i = 0; i < 2; i++)
      *(s16x8*)&Vs[(i * 32 + vr) * 128 + vxor] = vv[i];
    __syncthreads();

    if (kt + 128 < S_LEN) {
      const int k2 = kt + 128;
#pragma unroll
      for (int i = 0; i < 2; i++)
        kv[i] = *(const s16x8*)(Kp + (size_t)(b * S_LEN + k2 + i * 64 + sr) * DMODEL + h * 64 + sc8 * 8);
#pragma unroll
      for (int i = 0; i < 2; i++)
        vv[i] = *(const s16x8*)(Vt + (size_t)(bh * 64 + i * 32 + vr) * S_LEN + k2 + vc * 8);
    }

#pragma unroll
    for (int kvt = 0; kvt < 8; kvt++) {
      const int krow = kvt * 16 + l16;
      s16x8 ak0 = *(const s16x8*)&Ks[krow * 64 + (((0 + quad) ^ (l16 & 7)) << 3)];
      s16x8 ak1 = *(const s16x8*)&Ks[krow * 64 + (((4 + quad) ^ (l16 & 7)) << 3)];
      f32x4 sA;
      sA = __builtin_amdgcn_mfma_f32_16x16x32_bf16(ak0, aq[0], zf, 0, 0, 0);
      sA = __builtin_amdgcn_mfma_f32_16x16x32_bf16(ak1, aq[1], sA, 0, 0, 0);

      // sA already scaled (Q pre-scaled in GEMM epilogue)
      union { float f; uint32_t u; } e0, e1, e2, e3;
      e0.f = __builtin_amdgcn_exp2f(sA[0]);
      e1.f = __builtin_amdgcn_exp2f(sA[1]);
      e2.f = __builtin_amdgcn_exp2f(sA[2]);
      e3.f = __builtin_amdgcn_exp2f(sA[3]);
      l_r += (((e0.f + e1.f) + e2.f) + e3.f);

      // pack 4 bf16 (same rounding as f2bf: +0x8000, take high16) via v_perm
      union { uint32_t u[2]; s16x4 v; } pk;
      pk.u[0] = __builtin_amdgcn_perm(e1.u + 0x8000u, e0.u + 0x8000u, 0x07060302u);
      pk.u[1] = __builtin_amdgcn_perm(e3.u + 0x8000u, e2.u + 0x8000u, 0x07060302u);
      const s16x4 pf = pk.v;

      const int ch = kvt * 2 + (quad >> 1);
#pragma unroll
      for (int dt = 0; dt < 4; dt++) {
        const int row = dt * 16 + l16;
        s16x4 bv = *(const s16x4*)&Vs[row * 128 + ((ch ^ l16) << 3) + (quad & 1) * 4];
        o[dt] = __builtin_amdgcn_mfma_f32_16x16x16bf16_1k(pf, bv, o[dt], 0, 0, 0);
      }
    }
  }

  l_r += __shfl_xor(l_r, 16);
  l_r += __shfl_xor(l_r, 32);
#pragma unroll
  for (int r = 0; r < 4; r++) {
    const float linv = 1.f / __shfl(l_r, quad * 4 + r);
    const int row = s0 + wave * 16 + quad * 4 + r;
#pragma unroll
    for (int dt = 0; dt < 4; dt++)
      AO[(size_t)(b * S_LEN + row) * DMODEL + h * 64 + dt * 16 + l16] =
          f2bf(o[dt][r] * linv);
  }
}

// ---------------------------------------------------------------------------
extern "C" void kernel_launch(void* const* d_in, const int* in_sizes, int n_in,
                              void* d_out, int out_size, void* d_ws, size_t ws_size,
                              hipStream_t stream) {
  const float* query = (const float*)d_in[0];
  const float* key_  = (const float*)d_in[1];
  const float* value = (const float*)d_in[2];
  const float* W_q = (const float*)d_in[3];
  const float* b_q = (const float*)d_in[4];
  const float* W_k = (const float*)d_in[5];
  const float* b_k = (const float*)d_in[6];
  const float* W_v = (const float*)d_in[7];
  const float* b_v = (const float*)d_in[8];
  const float* W_o = (const float*)d_in[9];
  const float* b_o = (const float*)d_in[10];
  float* out = (float*)d_out;

  const int M = 2 * S_LEN;  // 4096
  const int N = DMODEL, K = DMODEL;
  const size_t WSZ = (size_t)DMODEL * DMODEL;   // 1,048,576
  const size_t SZ  = (size_t)M * DMODEL;        // 4,194,304

  u16* Wqb = (u16*)d_ws;         // 4 bf16 weights
  u16* Wkb = Wqb + WSZ;
  u16* Wvb = Wkb + WSZ;
  u16* Wob = Wvb + WSZ;
  u16* Qa  = Wob + WSZ;          // bf16 inputs (dead after QKV GEMM)
  u16* Ka  = Qa + SZ;
  u16* Va  = Ka + SZ;
  u16* Qp  = Va + SZ;            // projections
  u16* Kp  = Qp + SZ;
  u16* Vt  = Kp + SZ;            // [B,H,Dh,S] -- written directly by V-GEMM (VT path)
  u16* AO  = Qp;                 // aliases Qp (per-block disjoint read->write)

  Cvt7 cw;
  cw.s[0] = W_q;   cw.d[0] = Wqb; cw.n[0] = (int)WSZ;
  cw.s[1] = W_k;   cw.d[1] = Wkb; cw.n[1] = (int)WSZ;
  cw.s[2] = W_v;   cw.d[2] = Wvb; cw.n[2] = (int)WSZ;
  cw.s[3] = W_o;   cw.d[3] = Wob; cw.n[3] = (int)WSZ;
  cw.s[4] = query; cw.d[4] = Qa;  cw.n[4] = (int)SZ;
  cw.s[5] = key_;  cw.d[5] = Ka;  cw.n[5] = (int)SZ;
  cw.s[6] = value; cw.d[6] = Va;  cw.n[6] = (int)SZ;
  cvt7<<<dim3((int)(SZ / 2048), 7), 256, 0, stream>>>(cw);

  GemmBatch p1;
  p1.A[0] = Qa; p1.W[0] = Wqb; p1.Bv[0] = b_q; p1.C[0] = Qp;
  p1.A[1] = Ka; p1.W[1] = Wkb; p1.Bv[1] = b_k; p1.C[1] = Kp;
  p1.A[2] = Va; p1.W[2] = Wvb; p1.Bv[2] = b_v; p1.C[2] = Vt;  // unused (VT path)
  p1.vt = Vt;
  p1.scl[0] = 0.03125f * LOG2E;  // d_model^-0.5 * log2(e) folded into Q (fp32)
  p1.scl[1] = 1.0f;
  p1.scl[2] = 1.0f;
  gemm_bt<128, 128, false, true><<<dim3(N / 128, M / 128, 3), 256, 0, stream>>>(p1, M, N, K);

  attn_kernel<<<dim3(S_LEN / 128, 32), 512, 0, stream>>>(Qp, Kp, Vt, AO);

  GemmBatch p2;
  p2.A[0] = AO; p2.W[0] = Wob; p2.Bv[0] = b_o; p2.C[0] = out;
  p2.A[1] = AO; p2.W[1] = Wob; p2.Bv[1] = b_o; p2.C[1] = out;
  p2.A[2] = AO; p2.W[2] = Wob; p2.Bv[2] = b_o; p2.C[2] = out;
  p2.vt = nullptr;
  p2.scl[0] = 1.0f; p2.scl[1] = 1.0f; p2.scl[2] = 1.0f;
  gemm_bt<64, 64, true, false><<<dim3(N / 64, M / 64, 1), 256, 0, stream>>>(p2, M, N, K);
}

// Round 5
// 227.849 us; speedup vs baseline: 1.1476x; 1.0063x over previous
//
#include <hip/hip_runtime.h>
#include <stdint.h>

// MultiHeadAttention: B=2, S=2048, D=1024, H=16, Dh=64. fp32 in/out, bf16 MFMA inside.
// R13: attn LDS-traffic round (GEMMs unchanged from R12).
//  Theory: attn was LDS-read-bound (~8.4MB/CU through 128B/clk port ~ 90% busy).
//  Restructure 8 waves: was 8 q-tiles x 16 rows (full kv each); now 4 q-tiles x
//  32 rows x 2 kv-halves. Same MFMA/exp totals, HALF the K/V LDS reads (each
//  fragment feeds 2 q-subtiles). Wave pairs (w, w+4) merge partial O/l through
//  reused staging LDS once at the end (lane-coalesced, conflict-free).
// Carried: Q pre-scale in GEMM epilogue, raw v_exp_f32, v_perm P-pack, fused
// V-transpose, 64x64 O-GEMM.

typedef unsigned short u16;
typedef short s16x8 __attribute__((ext_vector_type(8)));   // 8 bf16 (4 VGPR)
typedef short s16x4 __attribute__((ext_vector_type(4)));   // 4 bf16 (2 VGPR)
typedef float f32x4 __attribute__((ext_vector_type(4)));
typedef u16 u16x4 __attribute__((ext_vector_type(4)));

#define S_LEN 2048
#define DMODEL 1024
#define LOG2E 1.44269504088896340736f

__device__ __forceinline__ u16 f2bf(float f) {
  union { float f; uint32_t u; } v; v.f = f;
  return (u16)((v.u + 0x8000u) >> 16);
}

__device__ __forceinline__ s16x8 ld8f(const float* s) {  // 8 fp32 -> 8 bf16
  f32x4 a = *(const f32x4*)s;
  f32x4 b = *(const f32x4*)(s + 4);
  s16x8 r;
  r[0] = (short)f2bf(a[0]); r[1] = (short)f2bf(a[1]);
  r[2] = (short)f2bf(a[2]); r[3] = (short)f2bf(a[3]);
  r[4] = (short)f2bf(b[0]); r[5] = (short)f2bf(b[1]);
  r[6] = (short)f2bf(b[2]); r[7] = (short)f2bf(b[3]);
  return r;
}

// async global->LDS, 16B/lane; HW scatters lane i to ldsbase + i*16
__device__ __forceinline__ void gl2lds16(const u16* g, u16* l) {
  __builtin_amdgcn_global_load_lds(
      (const __attribute__((address_space(1))) uint32_t*)g,
      (__attribute__((address_space(3))) uint32_t*)l, 16, 0, 0);
}

// ---------------------------------------------------------------------------
// fp32 -> bf16 conversion: 4 weights (1M elem) + 3 activations (4.19M elem).
// ---------------------------------------------------------------------------
struct Cvt7 { const float* s[7]; u16* d[7]; int n[7]; };

__global__ __launch_bounds__(256) void cvt7(Cvt7 p) {
  const int z = blockIdx.y;
  const int idx = blockIdx.x * 256 + threadIdx.x;
  if (idx * 8 < p.n[z])
    *(s16x8*)(p.d[z] + (size_t)idx * 8) = ld8f(p.s[z] + (size_t)idx * 8);
}

// ---------------------------------------------------------------------------
// GEMM: C[M,N] = (A[M,K] @ W[N,K]^T + bias[N]) * scl; A,W bf16, bias fp32.
// scl=1.0 for all but the Q projection (score scale folded in, fp32 pre-round).
// Template: BM x BN tile (BK=64 fixed), 4 waves as 2x2 of (BM/2 x BN/2).
// OUT_F32: fp32 C (O projection). VT: z==2 writes transposed bf16 to p.vt.
// ---------------------------------------------------------------------------
struct GemmBatch {
  const u16* A[3]; const u16* W[3]; const float* Bv[3]; void* C[3];
  u16* vt;       // VT destination: Vt[(b*16+h)*64+dh][s], row stride S_LEN
  float scl[3];  // epilogue scale (fp32, applied before f2bf round)
};

template <int BM, int BN, bool OUT_F32, bool VT>
__global__ __launch_bounds__(256) void gemm_bt(GemmBatch p, int M, int N, int K) {
  static_assert(!VT || (BM == 128 && BN == 128), "VT epilogue assumes 128x128");
  constexpr int MI = BM / 32, NJ = BN / 32;   // fragment repeats per wave
  constexpr int TS = BM + 8;                  // VT transpose stride (u16), 16B-aligned
  constexpr int AB = BM * 64 + BN * 64;
  constexpr int TB = VT ? BN * TS : 0;
  constexpr int SM = AB > TB ? AB : TB;
  __shared__ u16 smem[SM];
  u16* const As = smem;
  u16* const Ws = smem + BM * 64;

  const int z = blockIdx.z;
  const u16* __restrict__ A      = p.A[z];
  const u16* __restrict__ W      = p.W[z];
  const float* __restrict__ bias = p.Bv[z];
  const float scl = p.scl[z];

  const int tid = threadIdx.x;
  const int wave = tid >> 6, lane = tid & 63;
  const int quad = lane >> 4, l16 = lane & 15;
  const int bm = blockIdx.y * BM, bn = blockIdx.x * BN;
  const int wr = (wave >> 1) * (BM / 2), wc = (wave & 1) * (BN / 2);
  const int sr8 = lane >> 3;
  const int slc = (lane & 7) ^ sr8;           // logical k-chunk to fetch
  const int srow = wave * 8 + sr8;            // row within 32-row stripe

  f32x4 acc[MI][NJ];
#pragma unroll
  for (int i = 0; i < MI; i++)
#pragma unroll
    for (int j = 0; j < NJ; j++) acc[i][j] = {0.f, 0.f, 0.f, 0.f};

  const u16* Ab = A + (size_t)bm * K;
  const u16* Wb = W + (size_t)bn * K;

  for (int kt = 0; kt < K; kt += 64) {
    __syncthreads();  // previous iteration's LDS reads complete
#pragma unroll
    for (int i = 0; i < MI; i++)
      gl2lds16(Ab + (size_t)(i * 32 + srow) * K + kt + slc * 8,
               &As[(i * 32 + wave * 8) * 64]);
#pragma unroll
    for (int i = 0; i < NJ; i++)
      gl2lds16(Wb + (size_t)(i * 32 + srow) * K + kt + slc * 8,
               &Ws[(i * 32 + wave * 8) * 64]);
    __syncthreads();  // drains vmcnt (async loads) + LDS visible

#pragma unroll
    for (int ks = 0; ks < 2; ks++) {
      const int ch = ks * 4 + quad;  // logical chunk of this fragment
      s16x8 a[MI], b[NJ];
#pragma unroll
      for (int t = 0; t < MI; t++)
        a[t] = *(const s16x8*)&As[(wr + t * 16 + l16) * 64 + ((ch ^ (l16 & 7)) << 3)];
#pragma unroll
      for (int t = 0; t < NJ; t++)
        b[t] = *(const s16x8*)&Ws[(wc + t * 16 + l16) * 64 + ((ch ^ (l16 & 7)) << 3)];
#pragma unroll
      for (int i = 0; i < MI; i++)
#pragma unroll
        for (int j = 0; j < NJ; j++)
          acc[i][j] = __builtin_amdgcn_mfma_f32_16x16x32_bf16(a[i], b[j], acc[i][j], 0, 0, 0);
    }
  }

  if (VT && z == 2) {
    // ---- fused V transpose: acc -> LDS [col][row] -> Vt[d-row][s] ----
    __syncthreads();               // all waves done reading As/Ws
    u16* const T = smem;           // [BN][TS]
#pragma unroll
    for (int j = 0; j < NJ; j++) {
      const int c = wc + j * 16 + l16;
      const float bv = bias[bn + c];
#pragma unroll
      for (int i = 0; i < MI; i++) {
        const int r0 = wr + i * 16 + quad * 4;
        u16x4 t4;
#pragma unroll
        for (int r = 0; r < 4; r++) t4[r] = f2bf((acc[i][j][r] + bv) * scl);
        *(u16x4*)&T[c * TS + r0] = t4;
      }
    }
    __syncthreads();
    // thread -> (c = tid>>1, half = tid&1): 64 contiguous s per thread
    const int c = tid >> 1, half = tid & 1;
    const int b_ = bm >> 11;                 // batch (2048 rows each, 128 | 2048)
    const int sb = (bm & 2047) + half * 64;  // s within batch
    u16* dst = p.vt + (size_t)(b_ * 1024 + bn + c) * S_LEN + sb;
    const u16* srcT = &T[c * TS + half * 64];
#pragma unroll
    for (int k = 0; k < 8; k++)
      *(s16x8*)(dst + k * 8) = *(const s16x8*)(srcT + k * 8);
  } else {
    // epilogue: C/D layout row = quad*4 + reg, col = lane&15
#pragma unroll
    for (int j = 0; j < NJ; j++) {
      const int col = bn + wc + j * 16 + l16;
      const float bv = bias[col];
#pragma unroll
      for (int i = 0; i < MI; i++) {
        const int row0 = bm + wr + i * 16 + quad * 4;
#pragma unroll
        for (int r = 0; r < 4; r++) {
          const float val = (acc[i][j][r] + bv) * scl;
          if (OUT_F32)
            ((float*)p.C[z])[(size_t)(row0 + r) * N + col] = val;
          else
            ((u16*)p.C[z])[(size_t)(row0 + r) * N + col] = f2bf(val);
        }
      }
    }
  }
}

// ---------------------------------------------------------------------------
// Flash attention R13: 512 threads = 8 waves = 4 q-tiles(32 rows) x 2 kv-halves.
// Each wave: 32 q-rows x 64 kv per ktile -> each K/V LDS fragment feeds 2
// q-subtiles (half the LDS reads of R12). Wave pairs (w, w+4) merge O/l via
// reused staging LDS at the end. Q pre-scaled; exp2 = raw v_exp_f32; P-pack
// via v_perm. Grid (16,32); 48KB LDS -> 2 blocks/CU.
// ---------------------------------------------------------------------------
__global__ __launch_bounds__(512, 4) void attn_kernel(const u16* __restrict__ Qp,
                                                      const u16* __restrict__ Kp,
                                                      const u16* __restrict__ Vt,
                                                      u16* __restrict__ AO) {
  __shared__ u16 smem[24576];    // 48 KB
  u16* const Qs = smem;          // [q:128][d:64]  16 KB, 8-chunk XOR swizzle
  u16* const Ks = smem + 8192;   // [kv:128][d:64] 16 KB, 8-chunk XOR swizzle
  u16* const Vs = smem + 16384;  // [d:64][kv:128] 16 KB, 16-chunk XOR swizzle

  const int tid = threadIdx.x;
  const int wave = tid >> 6, lane = tid & 63;
  const int quad = lane >> 4, l16 = lane & 15;
  const int bh = blockIdx.y, b = bh >> 4, h = bh & 15;
  const int s0 = blockIdx.x * 128;
  const int qw = wave & 3;        // q-tile index (32 rows each)
  const int kvh = wave >> 2;      // kv half (64 kv rows each)

  const int sr = tid >> 3, sc8 = tid & 7;
  const int sxor = (sc8 ^ (sr & 7)) << 3;
  const int vr = tid >> 4, vc = tid & 15;
  const int vxor = (vc ^ (vr & 15)) << 3;

  // ---- Q stage (cooperative, 128 rows) + per-wave fragments (32 rows) ----
#pragma unroll
  for (int i = 0; i < 2; i++) {
    const int rr = i * 64 + sr;
    s16x8 qv = *(const s16x8*)(Qp + (size_t)(b * S_LEN + s0 + rr) * DMODEL + h * 64 + sc8 * 8);
    *(s16x8*)&Qs[rr * 64 + sxor] = qv;
  }
  __syncthreads();

  s16x8 aq[2][2];  // [ks][rt]
#pragma unroll
  for (int ks = 0; ks < 2; ks++)
#pragma unroll
    for (int rt = 0; rt < 2; rt++) {
      const int row = qw * 32 + rt * 16 + l16;
      const int ch = ks * 4 + quad;
      aq[ks][rt] = *(const s16x8*)&Qs[row * 64 + ((ch ^ (l16 & 7)) << 3)];
    }

  // ---- K/V register prefetch for kt=0 (cooperative staging, unchanged) ----
  s16x8 kv[2], vv[2];
#pragma unroll
  for (int i = 0; i < 2; i++)
    kv[i] = *(const s16x8*)(Kp + (size_t)(b * S_LEN + i * 64 + sr) * DMODEL + h * 64 + sc8 * 8);
#pragma unroll
  for (int i = 0; i < 2; i++)
    vv[i] = *(const s16x8*)(Vt + (size_t)(bh * 64 + i * 32 + vr) * S_LEN + vc * 8);

  f32x4 o[2][4];
  float l_r[2] = {0.f, 0.f};
#pragma unroll
  for (int rt = 0; rt < 2; rt++)
#pragma unroll
    for (int dt = 0; dt < 4; dt++) o[rt][dt] = {0.f, 0.f, 0.f, 0.f};

  const f32x4 zf = {0.f, 0.f, 0.f, 0.f};

  for (int kt = 0; kt < S_LEN; kt += 128) {
    __syncthreads();
#pragma unroll
    for (int i = 0; i < 2; i++)
      *(s16x8*)&Ks[(i * 64 + sr) * 64 + sxor] = kv[i];
#pragma unroll
    for (int i = 0; i < 2; i++)
      *(s16x8*)&Vs[(i * 32 + vr) * 128 + vxor] = vv[i];
    __syncthreads();

    if (kt + 128 < S_LEN) {
      const int k2 = kt + 128;
#pragma unroll
      for (int i = 0; i < 2; i++)
        kv[i] = *(const s16x8*)(Kp + (size_t)(b * S_LEN + k2 + i * 64 + sr) * DMODEL + h * 64 + sc8 * 8);
#pragma unroll
      for (int i = 0; i < 2; i++)
        vv[i] = *(const s16x8*)(Vt + (size_t)(bh * 64 + i * 32 + vr) * S_LEN + k2 + vc * 8);
    }

    // this wave's kv half: rows kvh*64 .. kvh*64+63 (4 subtiles of 16)
#pragma unroll
    for (int kvt = 0; kvt < 4; kvt++) {
      const int krow = kvh * 64 + kvt * 16 + l16;   // krow&7 == l16&7
      s16x8 ak0 = *(const s16x8*)&Ks[krow * 64 + (((0 + quad) ^ (l16 & 7)) << 3)];
      s16x8 ak1 = *(const s16x8*)&Ks[krow * 64 + (((4 + quad) ^ (l16 & 7)) << 3)];

      s16x4 pf[2];
#pragma unroll
      for (int rt = 0; rt < 2; rt++) {
        f32x4 sA;
        sA = __builtin_amdgcn_mfma_f32_16x16x32_bf16(ak0, aq[0][rt], zf, 0, 0, 0);
        sA = __builtin_amdgcn_mfma_f32_16x16x32_bf16(ak1, aq[1][rt], sA, 0, 0, 0);

        union { float f; uint32_t u; } e0, e1, e2, e3;
        e0.f = __builtin_amdgcn_exp2f(sA[0]);
        e1.f = __builtin_amdgcn_exp2f(sA[1]);
        e2.f = __builtin_amdgcn_exp2f(sA[2]);
        e3.f = __builtin_amdgcn_exp2f(sA[3]);
        l_r[rt] += (((e0.f + e1.f) + e2.f) + e3.f);

        union { uint32_t u[2]; s16x4 v; } pk;
        pk.u[0] = __builtin_amdgcn_perm(e1.u + 0x8000u, e0.u + 0x8000u, 0x07060302u);
        pk.u[1] = __builtin_amdgcn_perm(e3.u + 0x8000u, e2.u + 0x8000u, 0x07060302u);
        pf[rt] = pk.v;
      }

      const int ch = kvh * 8 + kvt * 2 + (quad >> 1);
#pragma unroll
      for (int dt = 0; dt < 4; dt++) {
        const int row = dt * 16 + l16;
        s16x4 bv = *(const s16x4*)&Vs[row * 128 + ((ch ^ l16) << 3) + (quad & 1) * 4];
        o[0][dt] = __builtin_amdgcn_mfma_f32_16x16x16bf16_1k(pf[0], bv, o[0][dt], 0, 0, 0);
        o[1][dt] = __builtin_amdgcn_mfma_f32_16x16x16bf16_1k(pf[1], bv, o[1][dt], 0, 0, 0);
      }
    }
  }

  // intra-wave l reduction (sum over quads -> value depends on l16 only)
#pragma unroll
  for (int rt = 0; rt < 2; rt++) {
    l_r[rt] += __shfl_xor(l_r[rt], 16);
    l_r[rt] += __shfl_xor(l_r[rt], 32);
  }

  // ---- cross-half merge: waves 4..7 dump O/l into reused staging LDS ----
  __syncthreads();  // all LDS reads of last ktile complete
  f32x4* const mrgO = (f32x4*)smem;            // [rt*4+dt][w*64+lane], 32 KB
  float* const mrgL = (float*)smem + 8192;     // [rt][w*64+lane], 2 KB @ 32 KB
  if (wave >= 4) {
    const int w = wave - 4;
#pragma unroll
    for (int rt = 0; rt < 2; rt++) {
#pragma unroll
      for (int dt = 0; dt < 4; dt++)
        mrgO[(rt * 4 + dt) * 256 + w * 64 + lane] = o[rt][dt];
      mrgL[rt * 256 + w * 64 + lane] = l_r[rt];
    }
  }
  __syncthreads();
  if (wave < 4) {
#pragma unroll
    for (int rt = 0; rt < 2; rt++) {
#pragma unroll
      for (int dt = 0; dt < 4; dt++) {
        f32x4 ov = mrgO[(rt * 4 + dt) * 256 + wave * 64 + lane];
        o[rt][dt] += ov;
      }
      l_r[rt] += mrgL[rt * 256 + wave * 64 + lane];
    }
#pragma unroll
    for (int rt = 0; rt < 2; rt++) {
#pragma unroll
      for (int r = 0; r < 4; r++) {
        const float linv = 1.f / __shfl(l_r[rt], quad * 4 + r);
        const int row = s0 + qw * 32 + rt * 16 + quad * 4 + r;
#pragma unroll
        for (int dt = 0; dt < 4; dt++)
          AO[(size_t)(b * S_LEN + row) * DMODEL + h * 64 + dt * 16 + l16] =
              f2bf(o[rt][dt][r] * linv);
      }
    }
  }
}

// ---------------------------------------------------------------------------
extern "C" void kernel_launch(void* const* d_in, const int* in_sizes, int n_in,
                              void* d_out, int out_size, void* d_ws, size_t ws_size,
                              hipStream_t stream) {
  const float* query = (const float*)d_in[0];
  const float* key_  = (const float*)d_in[1];
  const float* value = (const float*)d_in[2];
  const float* W_q = (const float*)d_in[3];
  const float* b_q = (const float*)d_in[4];
  const float* W_k = (const float*)d_in[5];
  const float* b_k = (const float*)d_in[6];
  const float* W_v = (const float*)d_in[7];
  const float* b_v = (const float*)d_in[8];
  const float* W_o = (const float*)d_in[9];
  const float* b_o = (const float*)d_in[10];
  float* out = (float*)d_out;

  const int M = 2 * S_LEN;  // 4096
  const int N = DMODEL, K = DMODEL;
  const size_t WSZ = (size_t)DMODEL * DMODEL;   // 1,048,576
  const size_t SZ  = (size_t)M * DMODEL;        // 4,194,304

  u16* Wqb = (u16*)d_ws;         // 4 bf16 weights
  u16* Wkb = Wqb + WSZ;
  u16* Wvb = Wkb + WSZ;
  u16* Wob = Wvb + WSZ;
  u16* Qa  = Wob + WSZ;          // bf16 inputs (dead after QKV GEMM)
  u16* Ka  = Qa + SZ;
  u16* Va  = Ka + SZ;
  u16* Qp  = Va + SZ;            // projections
  u16* Kp  = Qp + SZ;
  u16* Vt  = Kp + SZ;            // [B,H,Dh,S] -- written directly by V-GEMM (VT path)
  u16* AO  = Qp;                 // aliases Qp (per-block disjoint read->write)

  Cvt7 cw;
  cw.s[0] = W_q;   cw.d[0] = Wqb; cw.n[0] = (int)WSZ;
  cw.s[1] = W_k;   cw.d[1] = Wkb; cw.n[1] = (int)WSZ;
  cw.s[2] = W_v;   cw.d[2] = Wvb; cw.n[2] = (int)WSZ;
  cw.s[3] = W_o;   cw.d[3] = Wob; cw.n[3] = (int)WSZ;
  cw.s[4] = query; cw.d[4] = Qa;  cw.n[4] = (int)SZ;
  cw.s[5] = key_;  cw.d[5] = Ka;  cw.n[5] = (int)SZ;
  cw.s[6] = value; cw.d[6] = Va;  cw.n[6] = (int)SZ;
  cvt7<<<dim3((int)(SZ / 2048), 7), 256, 0, stream>>>(cw);

  GemmBatch p1;
  p1.A[0] = Qa; p1.W[0] = Wqb; p1.Bv[0] = b_q; p1.C[0] = Qp;
  p1.A[1] = Ka; p1.W[1] = Wkb; p1.Bv[1] = b_k; p1.C[1] = Kp;
  p1.A[2] = Va; p1.W[2] = Wvb; p1.Bv[2] = b_v; p1.C[2] = Vt;  // unused (VT path)
  p1.vt = Vt;
  p1.scl[0] = 0.03125f * LOG2E;  // d_model^-0.5 * log2(e) folded into Q (fp32)
  p1.scl[1] = 1.0f;
  p1.scl[2] = 1.0f;
  gemm_bt<128, 128, false, true><<<dim3(N / 128, M / 128, 3), 256, 0, stream>>>(p1, M, N, K);

  attn_kernel<<<dim3(S_LEN / 128, 32), 512, 0, stream>>>(Qp, Kp, Vt, AO);

  GemmBatch p2;
  p2.A[0] = AO; p2.W[0] = Wob; p2.Bv[0] = b_o; p2.C[0] = out;
  p2.A[1] = AO; p2.W[1] = Wob; p2.Bv[1] = b_o; p2.C[1] = out;
  p2.A[2] = AO; p2.W[2] = Wob; p2.Bv[2] = b_o; p2.C[2] = out;
  p2.vt = nullptr;
  p2.scl[0] = 1.0f; p2.scl[1] = 1.0f; p2.scl[2] = 1.0f;
  gemm_bt<64, 64, true, false><<<dim3(N / 64, M / 64, 1), 256, 0, stream>>>(p2, M, N, K);
}

// Round 7
// 227.813 us; speedup vs baseline: 1.1478x; 1.0002x over previous
//
#include <hip/hip_runtime.h>
#include <stdint.h>

// MultiHeadAttention: B=2, S=2048, D=1024, H=16, Dh=64. fp32 in/out, bf16 MFMA inside.
// R14 (resubmit; previous run died on container infra, no data): attn software-
// pipeline round (GEMMs unchanged from R13).
//  Theory: R13 counters show sum-of-pipes ~= dispatch time (MFMA 36%, VALU 40%,
//  LDS ~20%, none dominant) -> waves are phase-locked on the serial QK->exp->PV
//  chain; pipes idle alternately. Fix: issue QK(t+1) MFMAs before softmax+PV(t)
//  (T15 mechanism) so MFMA pipe computes under the exp/pack VALU phase within
//  each wave. +8 VGPR for the in-flight sA pair; numerics identical.
// Carried: 4 q-tiles x 2 kv-halves wave layout, end-of-kernel O/l merge,
// Q pre-scale in GEMM epilogue, raw v_exp_f32, v_perm P-pack, fused
// V-transpose, 64x64 O-GEMM.

typedef unsigned short u16;
typedef short s16x8 __attribute__((ext_vector_type(8)));   // 8 bf16 (4 VGPR)
typedef short s16x4 __attribute__((ext_vector_type(4)));   // 4 bf16 (2 VGPR)
typedef float f32x4 __attribute__((ext_vector_type(4)));
typedef u16 u16x4 __attribute__((ext_vector_type(4)));

#define S_LEN 2048
#define DMODEL 1024
#define LOG2E 1.44269504088896340736f

__device__ __forceinline__ u16 f2bf(float f) {
  union { float f; uint32_t u; } v; v.f = f;
  return (u16)((v.u + 0x8000u) >> 16);
}

__device__ __forceinline__ s16x8 ld8f(const float* s) {  // 8 fp32 -> 8 bf16
  f32x4 a = *(const f32x4*)s;
  f32x4 b = *(const f32x4*)(s + 4);
  s16x8 r;
  r[0] = (short)f2bf(a[0]); r[1] = (short)f2bf(a[1]);
  r[2] = (short)f2bf(a[2]); r[3] = (short)f2bf(a[3]);
  r[4] = (short)f2bf(b[0]); r[5] = (short)f2bf(b[1]);
  r[6] = (short)f2bf(b[2]); r[7] = (short)f2bf(b[3]);
  return r;
}

// async global->LDS, 16B/lane; HW scatters lane i to ldsbase + i*16
__device__ __forceinline__ void gl2lds16(const u16* g, u16* l) {
  __builtin_amdgcn_global_load_lds(
      (const __attribute__((address_space(1))) uint32_t*)g,
      (__attribute__((address_space(3))) uint32_t*)l, 16, 0, 0);
}

// ---------------------------------------------------------------------------
// fp32 -> bf16 conversion: 4 weights (1M elem) + 3 activations (4.19M elem).
// ---------------------------------------------------------------------------
struct Cvt7 { const float* s[7]; u16* d[7]; int n[7]; };

__global__ __launch_bounds__(256) void cvt7(Cvt7 p) {
  const int z = blockIdx.y;
  const int idx = blockIdx.x * 256 + threadIdx.x;
  if (idx * 8 < p.n[z])
    *(s16x8*)(p.d[z] + (size_t)idx * 8) = ld8f(p.s[z] + (size_t)idx * 8);
}

// ---------------------------------------------------------------------------
// GEMM: C[M,N] = (A[M,K] @ W[N,K]^T + bias[N]) * scl; A,W bf16, bias fp32.
// scl=1.0 for all but the Q projection (score scale folded in, fp32 pre-round).
// Template: BM x BN tile (BK=64 fixed), 4 waves as 2x2 of (BM/2 x BN/2).
// OUT_F32: fp32 C (O projection). VT: z==2 writes transposed bf16 to p.vt.
// ---------------------------------------------------------------------------
struct GemmBatch {
  const u16* A[3]; const u16* W[3]; const float* Bv[3]; void* C[3];
  u16* vt;       // VT destination: Vt[(b*16+h)*64+dh][s], row stride S_LEN
  float scl[3];  // epilogue scale (fp32, applied before f2bf round)
};

template <int BM, int BN, bool OUT_F32, bool VT>
__global__ __launch_bounds__(256) void gemm_bt(GemmBatch p, int M, int N, int K) {
  static_assert(!VT || (BM == 128 && BN == 128), "VT epilogue assumes 128x128");
  constexpr int MI = BM / 32, NJ = BN / 32;   // fragment repeats per wave
  constexpr int TS = BM + 8;                  // VT transpose stride (u16), 16B-aligned
  constexpr int AB = BM * 64 + BN * 64;
  constexpr int TB = VT ? BN * TS : 0;
  constexpr int SM = AB > TB ? AB : TB;
  __shared__ u16 smem[SM];
  u16* const As = smem;
  u16* const Ws = smem + BM * 64;

  const int z = blockIdx.z;
  const u16* __restrict__ A      = p.A[z];
  const u16* __restrict__ W      = p.W[z];
  const float* __restrict__ bias = p.Bv[z];
  const float scl = p.scl[z];

  const int tid = threadIdx.x;
  const int wave = tid >> 6, lane = tid & 63;
  const int quad = lane >> 4, l16 = lane & 15;
  const int bm = blockIdx.y * BM, bn = blockIdx.x * BN;
  const int wr = (wave >> 1) * (BM / 2), wc = (wave & 1) * (BN / 2);
  const int sr8 = lane >> 3;
  const int slc = (lane & 7) ^ sr8;           // logical k-chunk to fetch
  const int srow = wave * 8 + sr8;            // row within 32-row stripe

  f32x4 acc[MI][NJ];
#pragma unroll
  for (int i = 0; i < MI; i++)
#pragma unroll
    for (int j = 0; j < NJ; j++) acc[i][j] = {0.f, 0.f, 0.f, 0.f};

  const u16* Ab = A + (size_t)bm * K;
  const u16* Wb = W + (size_t)bn * K;

  for (int kt = 0; kt < K; kt += 64) {
    __syncthreads();  // previous iteration's LDS reads complete
#pragma unroll
    for (int i = 0; i < MI; i++)
      gl2lds16(Ab + (size_t)(i * 32 + srow) * K + kt + slc * 8,
               &As[(i * 32 + wave * 8) * 64]);
#pragma unroll
    for (int i = 0; i < NJ; i++)
      gl2lds16(Wb + (size_t)(i * 32 + srow) * K + kt + slc * 8,
               &Ws[(i * 32 + wave * 8) * 64]);
    __syncthreads();  // drains vmcnt (async loads) + LDS visible

#pragma unroll
    for (int ks = 0; ks < 2; ks++) {
      const int ch = ks * 4 + quad;  // logical chunk of this fragment
      s16x8 a[MI], b[NJ];
#pragma unroll
      for (int t = 0; t < MI; t++)
        a[t] = *(const s16x8*)&As[(wr + t * 16 + l16) * 64 + ((ch ^ (l16 & 7)) << 3)];
#pragma unroll
      for (int t = 0; t < NJ; t++)
        b[t] = *(const s16x8*)&Ws[(wc + t * 16 + l16) * 64 + ((ch ^ (l16 & 7)) << 3)];
#pragma unroll
      for (int i = 0; i < MI; i++)
#pragma unroll
        for (int j = 0; j < NJ; j++)
          acc[i][j] = __builtin_amdgcn_mfma_f32_16x16x32_bf16(a[i], b[j], acc[i][j], 0, 0, 0);
    }
  }

  if (VT && z == 2) {
    // ---- fused V transpose: acc -> LDS [col][row] -> Vt[d-row][s] ----
    __syncthreads();               // all waves done reading As/Ws
    u16* const T = smem;           // [BN][TS]
#pragma unroll
    for (int j = 0; j < NJ; j++) {
      const int c = wc + j * 16 + l16;
      const float bv = bias[bn + c];
#pragma unroll
      for (int i = 0; i < MI; i++) {
        const int r0 = wr + i * 16 + quad * 4;
        u16x4 t4;
#pragma unroll
        for (int r = 0; r < 4; r++) t4[r] = f2bf((acc[i][j][r] + bv) * scl);
        *(u16x4*)&T[c * TS + r0] = t4;
      }
    }
    __syncthreads();
    // thread -> (c = tid>>1, half = tid&1): 64 contiguous s per thread
    const int c = tid >> 1, half = tid & 1;
    const int b_ = bm >> 11;                 // batch (2048 rows each, 128 | 2048)
    const int sb = (bm & 2047) + half * 64;  // s within batch
    u16* dst = p.vt + (size_t)(b_ * 1024 + bn + c) * S_LEN + sb;
    const u16* srcT = &T[c * TS + half * 64];
#pragma unroll
    for (int k = 0; k < 8; k++)
      *(s16x8*)(dst + k * 8) = *(const s16x8*)(srcT + k * 8);
  } else {
    // epilogue: C/D layout row = quad*4 + reg, col = lane&15
#pragma unroll
    for (int j = 0; j < NJ; j++) {
      const int col = bn + wc + j * 16 + l16;
      const float bv = bias[col];
#pragma unroll
      for (int i = 0; i < MI; i++) {
        const int row0 = bm + wr + i * 16 + quad * 4;
#pragma unroll
        for (int r = 0; r < 4; r++) {
          const float val = (acc[i][j][r] + bv) * scl;
          if (OUT_F32)
            ((float*)p.C[z])[(size_t)(row0 + r) * N + col] = val;
          else
            ((u16*)p.C[z])[(size_t)(row0 + r) * N + col] = f2bf(val);
        }
      }
    }
  }
}

// ---------------------------------------------------------------------------
// Flash attention R14: 512 threads = 8 waves = 4 q-tiles(32 rows) x 2 kv-halves.
// Inner loop software-pipelined: QK(t+1) MFMAs issued before softmax+PV(t) so
// the matrix pipe computes under the exp/pack VALU phase. Wave pairs (w, w+4)
// merge O/l via reused staging LDS at the end. Q pre-scaled; raw v_exp_f32;
// v_perm P-pack. Grid (16,32); 48KB LDS -> 2 blocks/CU.
// ---------------------------------------------------------------------------
__global__ __launch_bounds__(512, 4) void attn_kernel(const u16* __restrict__ Qp,
                                                      const u16* __restrict__ Kp,
                                                      const u16* __restrict__ Vt,
                                                      u16* __restrict__ AO) {
  __shared__ u16 smem[24576];    // 48 KB
  u16* const Qs = smem;          // [q:128][d:64]  16 KB, 8-chunk XOR swizzle
  u16* const Ks = smem + 8192;   // [kv:128][d:64] 16 KB, 8-chunk XOR swizzle
  u16* const Vs = smem + 16384;  // [d:64][kv:128] 16 KB, 16-chunk XOR swizzle

  const int tid = threadIdx.x;
  const int wave = tid >> 6, lane = tid & 63;
  const int quad = lane >> 4, l16 = lane & 15;
  const int bh = blockIdx.y, b = bh >> 4, h = bh & 15;
  const int s0 = blockIdx.x * 128;
  const int qw = wave & 3;        // q-tile index (32 rows each)
  const int kvh = wave >> 2;      // kv half (64 kv rows each)

  const int sr = tid >> 3, sc8 = tid & 7;
  const int sxor = (sc8 ^ (sr & 7)) << 3;
  const int vr = tid >> 4, vc = tid & 15;
  const int vxor = (vc ^ (vr & 15)) << 3;

  // ---- Q stage (cooperative, 128 rows) + per-wave fragments (32 rows) ----
#pragma unroll
  for (int i = 0; i < 2; i++) {
    const int rr = i * 64 + sr;
    s16x8 qv = *(const s16x8*)(Qp + (size_t)(b * S_LEN + s0 + rr) * DMODEL + h * 64 + sc8 * 8);
    *(s16x8*)&Qs[rr * 64 + sxor] = qv;
  }
  __syncthreads();

  s16x8 aq[2][2];  // [ks][rt]
#pragma unroll
  for (int ks = 0; ks < 2; ks++)
#pragma unroll
    for (int rt = 0; rt < 2; rt++) {
      const int row = qw * 32 + rt * 16 + l16;
      const int ch = ks * 4 + quad;
      aq[ks][rt] = *(const s16x8*)&Qs[row * 64 + ((ch ^ (l16 & 7)) << 3)];
    }

  // ---- K/V register prefetch for kt=0 (cooperative staging, unchanged) ----
  s16x8 kv[2], vv[2];
#pragma unroll
  for (int i = 0; i < 2; i++)
    kv[i] = *(const s16x8*)(Kp + (size_t)(b * S_LEN + i * 64 + sr) * DMODEL + h * 64 + sc8 * 8);
#pragma unroll
  for (int i = 0; i < 2; i++)
    vv[i] = *(const s16x8*)(Vt + (size_t)(bh * 64 + i * 32 + vr) * S_LEN + vc * 8);

  f32x4 o[2][4];
  float l_r[2] = {0.f, 0.f};
#pragma unroll
  for (int rt = 0; rt < 2; rt++)
#pragma unroll
    for (int dt = 0; dt < 4; dt++) o[rt][dt] = {0.f, 0.f, 0.f, 0.f};

  const f32x4 zf = {0.f, 0.f, 0.f, 0.f};

  for (int kt = 0; kt < S_LEN; kt += 128) {
    __syncthreads();
#pragma unroll
    for (int i = 0; i < 2; i++)
      *(s16x8*)&Ks[(i * 64 + sr) * 64 + sxor] = kv[i];
#pragma unroll
    for (int i = 0; i < 2; i++)
      *(s16x8*)&Vs[(i * 32 + vr) * 128 + vxor] = vv[i];
    __syncthreads();

    if (kt + 128 < S_LEN) {
      const int k2 = kt + 128;
#pragma unroll
      for (int i = 0; i < 2; i++)
        kv[i] = *(const s16x8*)(Kp + (size_t)(b * S_LEN + k2 + i * 64 + sr) * DMODEL + h * 64 + sc8 * 8);
#pragma unroll
      for (int i = 0; i < 2; i++)
        vv[i] = *(const s16x8*)(Vt + (size_t)(bh * 64 + i * 32 + vr) * S_LEN + k2 + vc * 8);
    }

    // ---- this wave's kv half: 4 subtiles of 16, software-pipelined ----
    f32x4 sA[2];
    {
      const int krow = kvh * 64 + l16;
      s16x8 ak0 = *(const s16x8*)&Ks[krow * 64 + (((0 + quad) ^ (l16 & 7)) << 3)];
      s16x8 ak1 = *(const s16x8*)&Ks[krow * 64 + (((4 + quad) ^ (l16 & 7)) << 3)];
      sA[0] = __builtin_amdgcn_mfma_f32_16x16x32_bf16(ak0, aq[0][0], zf, 0, 0, 0);
      sA[0] = __builtin_amdgcn_mfma_f32_16x16x32_bf16(ak1, aq[1][0], sA[0], 0, 0, 0);
      sA[1] = __builtin_amdgcn_mfma_f32_16x16x32_bf16(ak0, aq[0][1], zf, 0, 0, 0);
      sA[1] = __builtin_amdgcn_mfma_f32_16x16x32_bf16(ak1, aq[1][1], sA[1], 0, 0, 0);
    }
#pragma unroll
    for (int kvt = 0; kvt < 4; kvt++) {
      // QK for subtile kvt+1 issued FIRST (fills MFMA pipe under softmax VALU)
      f32x4 nA[2];
      if (kvt < 3) {
        const int krow = kvh * 64 + (kvt + 1) * 16 + l16;
        s16x8 ak0 = *(const s16x8*)&Ks[krow * 64 + (((0 + quad) ^ (l16 & 7)) << 3)];
        s16x8 ak1 = *(const s16x8*)&Ks[krow * 64 + (((4 + quad) ^ (l16 & 7)) << 3)];
        nA[0] = __builtin_amdgcn_mfma_f32_16x16x32_bf16(ak0, aq[0][0], zf, 0, 0, 0);
        nA[0] = __builtin_amdgcn_mfma_f32_16x16x32_bf16(ak1, aq[1][0], nA[0], 0, 0, 0);
        nA[1] = __builtin_amdgcn_mfma_f32_16x16x32_bf16(ak0, aq[0][1], zf, 0, 0, 0);
        nA[1] = __builtin_amdgcn_mfma_f32_16x16x32_bf16(ak1, aq[1][1], nA[1], 0, 0, 0);
      }

      // softmax (cur)
      s16x4 pf[2];
#pragma unroll
      for (int rt = 0; rt < 2; rt++) {
        union { float f; uint32_t u; } e0, e1, e2, e3;
        e0.f = __builtin_amdgcn_exp2f(sA[rt][0]);
        e1.f = __builtin_amdgcn_exp2f(sA[rt][1]);
        e2.f = __builtin_amdgcn_exp2f(sA[rt][2]);
        e3.f = __builtin_amdgcn_exp2f(sA[rt][3]);
        l_r[rt] += (((e0.f + e1.f) + e2.f) + e3.f);

        union { uint32_t u[2]; s16x4 v; } pk;
        pk.u[0] = __builtin_amdgcn_perm(e1.u + 0x8000u, e0.u + 0x8000u, 0x07060302u);
        pk.u[1] = __builtin_amdgcn_perm(e3.u + 0x8000u, e2.u + 0x8000u, 0x07060302u);
        pf[rt] = pk.v;
      }

      // PV (cur)
      const int ch = kvh * 8 + kvt * 2 + (quad >> 1);
#pragma unroll
      for (int dt = 0; dt < 4; dt++) {
        const int row = dt * 16 + l16;
        s16x4 bv = *(const s16x4*)&Vs[row * 128 + ((ch ^ l16) << 3) + (quad & 1) * 4];
        o[0][dt] = __builtin_amdgcn_mfma_f32_16x16x16bf16_1k(pf[0], bv, o[0][dt], 0, 0, 0);
        o[1][dt] = __builtin_amdgcn_mfma_f32_16x16x16bf16_1k(pf[1], bv, o[1][dt], 0, 0, 0);
      }

      if (kvt < 3) { sA[0] = nA[0]; sA[1] = nA[1]; }
    }
  }

  // intra-wave l reduction (sum over quads -> value depends on l16 only)
#pragma unroll
  for (int rt = 0; rt < 2; rt++) {
    l_r[rt] += __shfl_xor(l_r[rt], 16);
    l_r[rt] += __shfl_xor(l_r[rt], 32);
  }

  // ---- cross-half merge: waves 4..7 dump O/l into reused staging LDS ----
  __syncthreads();  // all LDS reads of last ktile complete
  f32x4* const mrgO = (f32x4*)smem;            // [rt*4+dt][w*64+lane], 32 KB
  float* const mrgL = (float*)smem + 8192;     // [rt][w*64+lane], 2 KB @ 32 KB
  if (wave >= 4) {
    const int w = wave - 4;
#pragma unroll
    for (int rt = 0; rt < 2; rt++) {
#pragma unroll
      for (int dt = 0; dt < 4; dt++)
        mrgO[(rt * 4 + dt) * 256 + w * 64 + lane] = o[rt][dt];
      mrgL[rt * 256 + w * 64 + lane] = l_r[rt];
    }
  }
  __syncthreads();
  if (wave < 4) {
#pragma unroll
    for (int rt = 0; rt < 2; rt++) {
#pragma unroll
      for (int dt = 0; dt < 4; dt++) {
        f32x4 ov = mrgO[(rt * 4 + dt) * 256 + wave * 64 + lane];
        o[rt][dt] += ov;
      }
      l_r[rt] += mrgL[rt * 256 + wave * 64 + lane];
    }
#pragma unroll
    for (int rt = 0; rt < 2; rt++) {
#pragma unroll
      for (int r = 0; r < 4; r++) {
        const float linv = 1.f / __shfl(l_r[rt], quad * 4 + r);
        const int row = s0 + qw * 32 + rt * 16 + quad * 4 + r;
#pragma unroll
        for (int dt = 0; dt < 4; dt++)
          AO[(size_t)(b * S_LEN + row) * DMODEL + h * 64 + dt * 16 + l16] =
              f2bf(o[rt][dt][r] * linv);
      }
    }
  }
}

// ---------------------------------------------------------------------------
extern "C" void kernel_launch(void* const* d_in, const int* in_sizes, int n_in,
                              void* d_out, int out_size, void* d_ws, size_t ws_size,
                              hipStream_t stream) {
  const float* query = (const float*)d_in[0];
  const float* key_  = (const float*)d_in[1];
  const float* value = (const float*)d_in[2];
  const float* W_q = (const float*)d_in[3];
  const float* b_q = (const float*)d_in[4];
  const float* W_k = (const float*)d_in[5];
  const float* b_k = (const float*)d_in[6];
  const float* W_v = (const float*)d_in[7];
  const float* b_v = (const float*)d_in[8];
  const float* W_o = (const float*)d_in[9];
  const float* b_o = (const float*)d_in[10];
  float* out = (float*)d_out;

  const int M = 2 * S_LEN;  // 4096
  const int N = DMODEL, K = DMODEL;
  const size_t WSZ = (size_t)DMODEL * DMODEL;   // 1,048,576
  const size_t SZ  = (size_t)M * DMODEL;        // 4,194,304

  u16* Wqb = (u16*)d_ws;         // 4 bf16 weights
  u16* Wkb = Wqb + WSZ;
  u16* Wvb = Wkb + WSZ;
  u16* Wob = Wvb + WSZ;
  u16* Qa  = Wob + WSZ;          // bf16 inputs (dead after QKV GEMM)
  u16* Ka  = Qa + SZ;
  u16* Va  = Ka + SZ;
  u16* Qp  = Va + SZ;            // projections
  u16* Kp  = Qp + SZ;
  u16* Vt  = Kp + SZ;            // [B,H,Dh,S] -- written directly by V-GEMM (VT path)
  u16* AO  = Qp;                 // aliases Qp (per-block disjoint read->write)

  Cvt7 cw;
  cw.s[0] = W_q;   cw.d[0] = Wqb; cw.n[0] = (int)WSZ;
  cw.s[1] = W_k;   cw.d[1] = Wkb; cw.n[1] = (int)WSZ;
  cw.s[2] = W_v;   cw.d[2] = Wvb; cw.n[2] = (int)WSZ;
  cw.s[3] = W_o;   cw.d[3] = Wob; cw.n[3] = (int)WSZ;
  cw.s[4] = query; cw.d[4] = Qa;  cw.n[4] = (int)SZ;
  cw.s[5] = key_;  cw.d[5] = Ka;  cw.n[5] = (int)SZ;
  cw.s[6] = value; cw.d[6] = Va;  cw.n[6] = (int)SZ;
  cvt7<<<dim3((int)(SZ / 2048), 7), 256, 0, stream>>>(cw);

  GemmBatch p1;
  p1.A[0] = Qa; p1.W[0] = Wqb; p1.Bv[0] = b_q; p1.C[0] = Qp;
  p1.A[1] = Ka; p1.W[1] = Wkb; p1.Bv[1] = b_k; p1.C[1] = Kp;
  p1.A[2] = Va; p1.W[2] = Wvb; p1.Bv[2] = b_v; p1.C[2] = Vt;  // unused (VT path)
  p1.vt = Vt;
  p1.scl[0] = 0.03125f * LOG2E;  // d_model^-0.5 * log2(e) folded into Q (fp32)
  p1.scl[1] = 1.0f;
  p1.scl[2] = 1.0f;
  gemm_bt<128, 128, false, true><<<dim3(N / 128, M / 128, 3), 256, 0, stream>>>(p1, M, N, K);

  attn_kernel<<<dim3(S_LEN / 128, 32), 512, 0, stream>>>(Qp, Kp, Vt, AO);

  GemmBatch p2;
  p2.A[0] = AO; p2.W[0] = Wob; p2.Bv[0] = b_o; p2.C[0] = out;
  p2.A[1] = AO; p2.W[1] = Wob; p2.Bv[1] = b_o; p2.C[1] = out;
  p2.A[2] = AO; p2.W[2] = Wob; p2.Bv[2] = b_o; p2.C[2] = out;
  p2.vt = nullptr;
  p2.scl[0] = 1.0f; p2.scl[1] = 1.0f; p2.scl[2] = 1.0f;
  gemm_bt<64, 64, true, false><<<dim3(N / 64, M / 64, 1), 256, 0, stream>>>(p2, M, N, K);
}